// Round 3
// baseline (1068.742 us; speedup 1.0000x reference)
//
#include <hip/hip_runtime.h>
#include <cmath>

#define T_TOK 4096
#define DM    512
#define DFF   2048
#define NE    16
#define PP    128

typedef __attribute__((ext_vector_type(8))) short bfrag;      // 8 bf16 (4 VGPRs)
typedef __attribute__((ext_vector_type(4))) float f32x4;
typedef __attribute__((ext_vector_type(8))) unsigned short us8;

__device__ __forceinline__ unsigned short f2bf(float f) {
  unsigned int u = __float_as_uint(f);
  unsigned int r = (u + 0x7FFFu + ((u >> 16) & 1u)) >> 16;
  return (unsigned short)r;
}
__device__ __forceinline__ float bf2f(unsigned short b) {
  return __uint_as_float(((unsigned int)b) << 16);
}

#define GLOAD_LDS16(g, l) __builtin_amdgcn_global_load_lds( \
    (const __attribute__((address_space(1))) void*)(g), \
    (__attribute__((address_space(3))) void*)(l), 16, 0, 0)

// ---------------------------------------------------------------------------
// f32 tiled SGEMM: C[M,N] = A[M,K] * B[N,K]^T + bias[N]   (routing chain, f32)
// ---------------------------------------------------------------------------
__global__ __launch_bounds__(256) void sgemm_nt_bias(
    const float* __restrict__ A, const float* __restrict__ B,
    const float* __restrict__ bias, float* __restrict__ C,
    int M, int N, int K)
{
  __shared__ __align__(16) float As[16][68];
  __shared__ __align__(16) float Bs[16][68];
  const int bm = blockIdx.x * 64;
  const int bn = blockIdx.y * 64;
  const int tid = threadIdx.x;
  const int tx = tid & 15;
  const int ty = tid >> 4;

  float acc[4][4] = {{0.f}};

  for (int k0 = 0; k0 < K; k0 += 16) {
    {
      int r  = tid >> 2;
      int c4 = (tid & 3) * 4;
      float4 v = *(const float4*)(A + (size_t)(bm + r) * K + k0 + c4);
      As[c4+0][r] = v.x; As[c4+1][r] = v.y; As[c4+2][r] = v.z; As[c4+3][r] = v.w;
    }
    {
      int r  = tid >> 2;
      int c4 = (tid & 3) * 4;
      float4 v = *(const float4*)(B + (size_t)(bn + r) * K + k0 + c4);
      Bs[c4+0][r] = v.x; Bs[c4+1][r] = v.y; Bs[c4+2][r] = v.z; Bs[c4+3][r] = v.w;
    }
    __syncthreads();
    #pragma unroll
    for (int k = 0; k < 16; ++k) {
      float4 a4 = *(const float4*)&As[k][ty*4];
      float4 b4 = *(const float4*)&Bs[k][tx*4];
      float a[4] = {a4.x, a4.y, a4.z, a4.w};
      float b[4] = {b4.x, b4.y, b4.z, b4.w};
      #pragma unroll
      for (int i = 0; i < 4; ++i)
        #pragma unroll
        for (int j = 0; j < 4; ++j)
          acc[i][j] += a[i] * b[j];
    }
    __syncthreads();
  }
  #pragma unroll
  for (int i = 0; i < 4; ++i) {
    int row = bm + ty*4 + i;
    #pragma unroll
    for (int j = 0; j < 4; ++j) {
      int col = bn + tx*4 + j;
      C[(size_t)row * N + col] = acc[i][j] + bias[col];
    }
  }
}

// ---------------------------------------------------------------------------
// GRU elementwise
// ---------------------------------------------------------------------------
__global__ void gru_elem(const float* __restrict__ gx, const float* __restrict__ gh,
                         const float* __restrict__ hprev, float* __restrict__ hout)
{
  int i = blockIdx.x * blockDim.x + threadIdx.x;
  int t = i >> 7, p = i & 127;
  const float* gxr = gx + (size_t)t * 384;
  const float* ghr = gh + (size_t)t * 384;
  float xr = gxr[p], xz = gxr[128 + p], xn = gxr[256 + p];
  float hr = ghr[p], hz = ghr[128 + p], hn = ghr[256 + p];
  float r = 1.f / (1.f + expf(-(xr + hr)));
  float z = 1.f / (1.f + expf(-(xz + hz)));
  float n = tanhf(xn + r * hn);
  hout[i] = (1.f - z) * n + z * hprev[i];
}

// ---------------------------------------------------------------------------
// Router: softmax -> top-2 (stable) -> renorm -> per-expert lists
// ---------------------------------------------------------------------------
__global__ void router_topk(const float* __restrict__ h, const float* __restrict__ Wr,
                            const float* __restrict__ br,
                            float* __restrict__ wgt, int* __restrict__ tokslot,
                            int* __restrict__ cnt)
{
  int wave = threadIdx.x >> 6;
  int lane = threadIdx.x & 63;
  int t = blockIdx.x * 4 + wave;

  float logit = 0.f;
  if (lane < NE) {
    const float* hr = h + (size_t)t * PP;
    const float* wr = Wr + (size_t)lane * PP;
    float s = 0.f;
    #pragma unroll 8
    for (int p = 0; p < PP; ++p) s += hr[p] * wr[p];
    logit = s + br[lane];
  }
  float l[NE];
  #pragma unroll
  for (int e = 0; e < NE; ++e) l[e] = __shfl(logit, e, 64);

  if (lane == 0) {
    float mx = l[0];
    #pragma unroll
    for (int e = 1; e < NE; ++e) mx = fmaxf(mx, l[e]);
    float p[NE];
    #pragma unroll
    for (int e = 0; e < NE; ++e) p[e] = expf(l[e] - mx);
    int i0 = 0; float m0 = p[0];
    #pragma unroll
    for (int e = 1; e < NE; ++e) { if (p[e] > m0) { m0 = p[e]; i0 = e; } }
    int i1 = -1; float m1 = -1.f;
    #pragma unroll
    for (int e = 0; e < NE; ++e) { if (e != i0 && p[e] > m1) { m1 = p[e]; i1 = e; } }
    float inv = 1.f / (m0 + m1);
    int pos0 = atomicAdd(&cnt[i0], 1);
    tokslot[(size_t)i0 * T_TOK + pos0] = (t << 1);
    wgt[(size_t)i0 * T_TOK + pos0] = m0 * inv;
    int pos1 = atomicAdd(&cnt[i1], 1);
    tokslot[(size_t)i1 * T_TOK + pos1] = (t << 1) | 1;
    wgt[(size_t)i1 * T_TOK + pos1] = m1 * inv;
  }
}

__global__ void zero_cnt(int* cnt) { if (threadIdx.x < NE) cnt[threadIdx.x] = 0; }

__global__ void calc_off(const int* __restrict__ cnt, int* __restrict__ offPad) {
  if (threadIdx.x == 0) {
    int s = 0;
    for (int e = 0; e < NE; ++e) { offPad[e] = s; s += (cnt[e] + 127) & ~127; }
    offPad[NE] = s;
  }
}

// ---------------------------------------------------------------------------
// Transpose+convert: in [E][K][N] f32 -> out [E][N][K] bf16  (64x64 tiles)
// ---------------------------------------------------------------------------
__global__ __launch_bounds__(256) void transpose_cvt(
    const float* __restrict__ in, unsigned short* __restrict__ out, int K, int N)
{
  __shared__ float tl[64][65];
  int e = blockIdx.z, kt = blockIdx.y, nt = blockIdx.x;
  const float* ib = in + (size_t)e * K * N + (size_t)(kt * 64) * N + nt * 64;
  int t = threadIdx.x;
  int r = t >> 2, c0 = (t & 3) * 16;
  #pragma unroll
  for (int i = 0; i < 4; ++i) {
    float4 v = *(const float4*)(ib + (size_t)r * N + c0 + i * 4);
    tl[r][c0+i*4+0] = v.x; tl[r][c0+i*4+1] = v.y;
    tl[r][c0+i*4+2] = v.z; tl[r][c0+i*4+3] = v.w;
  }
  __syncthreads();
  unsigned short* ob = out + (size_t)e * N * K + (size_t)(nt * 64) * K + kt * 64;
  #pragma unroll
  for (int i = 0; i < 2; ++i) {
    int u = t + i * 256;
    int n = u >> 3, k0 = (u & 7) * 8;
    us8 o;
    #pragma unroll
    for (int j = 0; j < 8; ++j) o[j] = f2bf(tl[k0 + j][n]);
    *(us8*)(ob + (size_t)n * K + k0) = o;
  }
}

// ---------------------------------------------------------------------------
// Gather routed tokens -> compact padded bf16 xg [rows][DM]
// ---------------------------------------------------------------------------
__global__ __launch_bounds__(256) void gather_x(
    const float* __restrict__ x, const int* __restrict__ tokslot,
    const int* __restrict__ cnt, const int* __restrict__ offPad,
    unsigned short* __restrict__ xg)
{
  int e = blockIdx.y;
  int n = cnt[e];
  int npad = (n + 127) & ~127;
  int r0 = blockIdx.x * 128;
  if (r0 >= npad) return;
  int t = threadIdx.x;
  int r = r0 + (t >> 1);
  int half = t & 1;
  unsigned short* orow = xg + (size_t)(offPad[e] + r) * DM + half * 256;
  if (r >= n) {
    us8 z = {0,0,0,0,0,0,0,0};
    #pragma unroll
    for (int i = 0; i < 32; ++i) *(us8*)(orow + i * 8) = z;
    return;
  }
  int tok = tokslot[(size_t)e * T_TOK + r] >> 1;
  const float* irow = x + (size_t)tok * DM + half * 256;
  #pragma unroll
  for (int i = 0; i < 32; ++i) {
    float4 a = *(const float4*)(irow + i * 8);
    float4 b = *(const float4*)(irow + i * 8 + 4);
    us8 o;
    o[0]=f2bf(a.x); o[1]=f2bf(a.y); o[2]=f2bf(a.z); o[3]=f2bf(a.w);
    o[4]=f2bf(b.x); o[5]=f2bf(b.y); o[6]=f2bf(b.z); o[7]=f2bf(b.w);
    *(us8*)(orow + i * 8) = o;
  }
}

// ---------------------------------------------------------------------------
// FUSED expert FFN: per (expert, 128-token tile, ff-chunk 512):
//   h = relu(xg @ W1t^T + b1)   (ff sub-iters of 128, h kept in LDS)
//   acc2 += h @ W2t_chunk^T     (W2 B-frags direct from global, prefetched)
//   pPart[z][slot][tok] = (acc2 + b2*[z==0]) * w   (bf16 partials)
// 1024 threads = 16 waves. GEMM1 waves 4Mx4N (32x32), GEMM2 waves 2Mx8N (64x64).
// ---------------------------------------------------------------------------
__global__ __launch_bounds__(1024) void expert_fused(
    const unsigned short* __restrict__ xg, const unsigned short* __restrict__ W1t,
    const float* __restrict__ b1,
    const unsigned short* __restrict__ W2t, const float* __restrict__ b2,
    const int* __restrict__ cnt, const int* __restrict__ offPad,
    const int* __restrict__ tokslot, const float* __restrict__ wgt,
    unsigned short* __restrict__ pPart)
{
  const int e = blockIdx.y;
  const int n = cnt[e];
  const int npad = (n + 127) & ~127;
  const int tile = blockIdx.x;
  if (tile * 128 >= npad) return;
  const int z = blockIdx.z;                  // ff range [z*512, z*512+512)

  __shared__ unsigned short xgs[128 * 64];   // 16 KB
  __shared__ unsigned short w1s[128 * 64];   // 16 KB
  __shared__ unsigned short hls[128 * 136];  // 34 KB (pad stride 136)
  __shared__ int   ltok[128];
  __shared__ float lw[128];

  const int t = threadIdx.x;
  const int lane = t & 63;
  const int wv = t >> 6;
  const int l15 = lane & 15, lg = lane >> 4;

  if (t < 128) {
    int idx = tile * 128 + t;
    if (idx < n) {
      ltok[t] = tokslot[(size_t)e * T_TOK + idx];
      lw[t]   = wgt[(size_t)e * T_TOK + idx];
    } else { ltok[t] = -1; lw[t] = 0.f; }
  }

  const int base = offPad[e] + tile * 128;
  const unsigned short* xgb = xg + (size_t)base * DM;
  const unsigned short* w2e = W2t + (size_t)e * DM * DFF;

  // GEMM1 wave tile: 32 tok x 32 ff
  const int wm1 = (wv & 3) * 32;
  const int wn1 = (wv >> 2) * 32;
  // GEMM2 wave tile: 64 tok x 64 dm
  const int wm2 = (wv & 1) * 64;
  const int wn2 = (wv >> 1) * 64;

  f32x4 acc2[4][4];
  #pragma unroll
  for (int i = 0; i < 4; ++i)
    #pragma unroll
    for (int j = 0; j < 4; ++j) acc2[i][j] = (f32x4){0.f, 0.f, 0.f, 0.f};

  // stage slot for this thread: slot index s = t (0..1023) -> (r = s>>3, c = s&7)
  const int sr = t >> 3, sc = t & 7;

  for (int it = 0; it < 4; ++it) {
    const int ff0 = z * 512 + it * 128;
    const unsigned short* w1b = W1t + ((size_t)e * DFF + ff0) * DM;

    f32x4 acc1[2][2];
    #pragma unroll
    for (int i = 0; i < 2; ++i)
      #pragma unroll
      for (int j = 0; j < 2; ++j) acc1[i][j] = (f32x4){0.f, 0.f, 0.f, 0.f};

    for (int kc = 0; kc < DM; kc += 64) {
      // stage xgs (1024 x 16B) + w1s (1024 x 16B): swizzled global source
      GLOAD_LDS16(xgb + (size_t)sr * DM + kc + ((sc ^ (sr & 7)) << 3), &xgs[t * 8]);
      GLOAD_LDS16(w1b + (size_t)sr * DM + kc + ((sc ^ (sr & 7)) << 3), &w1s[t * 8]);
      __syncthreads();
      #pragma unroll
      for (int kk = 0; kk < 2; ++kk) {
        int cidx = kk * 4 + lg;
        bfrag a[2], b[2];
        #pragma unroll
        for (int fi = 0; fi < 2; ++fi) {
          int row = wm1 + fi * 16 + l15;
          a[fi] = *(const bfrag*)&xgs[row * 64 + ((cidx ^ (row & 7)) << 3)];
        }
        #pragma unroll
        for (int fj = 0; fj < 2; ++fj) {
          int row = wn1 + fj * 16 + l15;
          b[fj] = *(const bfrag*)&w1s[row * 64 + ((cidx ^ (row & 7)) << 3)];
        }
        #pragma unroll
        for (int fi = 0; fi < 2; ++fi)
          #pragma unroll
          for (int fj = 0; fj < 2; ++fj)
            acc1[fi][fj] = __builtin_amdgcn_mfma_f32_16x16x32_bf16(a[fi], b[fj], acc1[fi][fj], 0, 0, 0);
      }
      __syncthreads();
    }

    // prefetch W2 B-fragments for this ff-iter (overlaps h-epilogue + barrier)
    bfrag bst[4][4];
    #pragma unroll
    for (int fj = 0; fj < 4; ++fj) {
      const unsigned short* src = w2e + (size_t)(wn2 + fj * 16 + l15) * DFF + ff0 + lg * 8;
      #pragma unroll
      for (int kk = 0; kk < 4; ++kk)
        bst[fj][kk] = *(const bfrag*)(src + kk * 32);
    }

    // h epilogue: relu(acc1 + b1) -> hls
    #pragma unroll
    for (int fj = 0; fj < 2; ++fj) {
      int col = wn1 + fj * 16 + l15;
      float bv = b1[(size_t)e * DFF + ff0 + col];
      #pragma unroll
      for (int fi = 0; fi < 2; ++fi) {
        #pragma unroll
        for (int rg = 0; rg < 4; ++rg) {
          int row = wm1 + fi * 16 + lg * 4 + rg;
          float v = acc1[fi][fj][rg] + bv;
          hls[row * 136 + col] = f2bf(v > 0.f ? v : 0.f);
        }
      }
    }
    __syncthreads();

    // GEMM2: acc2 += h[128][128] @ W2chunk^T
    #pragma unroll
    for (int kk = 0; kk < 4; ++kk) {
      bfrag a[4];
      #pragma unroll
      for (int fi = 0; fi < 4; ++fi) {
        int row = wm2 + fi * 16 + l15;
        a[fi] = *(const bfrag*)&hls[row * 136 + kk * 32 + lg * 8];
      }
      #pragma unroll
      for (int fi = 0; fi < 4; ++fi)
        #pragma unroll
        for (int fj = 0; fj < 4; ++fj)
          acc2[fi][fj] = __builtin_amdgcn_mfma_f32_16x16x32_bf16(a[fi], bst[fj][kk], acc2[fi][fj], 0, 0, 0);
    }
    __syncthreads();   // hls/xgs/w1s reads done before next iter overwrites
  }

  // epilogue: (acc2 [+ b2 if z==0]) * w -> pPart[z][slot][tok][dm] (bf16)
  #pragma unroll
  for (int fj = 0; fj < 4; ++fj) {
    int col = wn2 + fj * 16 + l15;
    float bv = (z == 0) ? b2[(size_t)e * DM + col] : 0.f;
    #pragma unroll
    for (int fi = 0; fi < 4; ++fi) {
      #pragma unroll
      for (int rg = 0; rg < 4; ++rg) {
        int r = wm2 + fi * 16 + lg * 4 + rg;
        int ts = ltok[r];
        if (ts < 0) continue;
        float v = (acc2[fi][fj][rg] + bv) * lw[r];
        pPart[((size_t)(z * 2 + (ts & 1)) * T_TOK + (ts >> 1)) * DM + col] = f2bf(v);
      }
    }
  }
}

// ---------------------------------------------------------------------------
// Combine: out[t][d] = sum over 8 bf16 partial planes
// ---------------------------------------------------------------------------
__global__ __launch_bounds__(256) void combine_out(
    const unsigned short* __restrict__ pPart, float* __restrict__ out)
{
  int i = blockIdx.x * blockDim.x + threadIdx.x;   // i < T*DM/8
  float s[8] = {0.f};
  #pragma unroll
  for (int pl = 0; pl < 8; ++pl) {
    us8 v = *(const us8*)&pPart[(size_t)pl * T_TOK * DM + (size_t)i * 8];
    #pragma unroll
    for (int j = 0; j < 8; ++j) s[j] += bf2f(v[j]);
  }
  float4* o = (float4*)(out + (size_t)i * 8);
  o[0] = make_float4(s[0], s[1], s[2], s[3]);
  o[1] = make_float4(s[4], s[5], s[6], s[7]);
}

// ---------------------------------------------------------------------------
extern "C" void kernel_launch(void* const* d_in, const int* in_sizes, int n_in,
                              void* d_out, int out_size, void* d_ws, size_t ws_size,
                              hipStream_t stream)
{
  const float* x      = (const float*)d_in[0];
  const float* h_prev = (const float*)d_in[1];
  const float* Wp     = (const float*)d_in[2];
  const float* bp     = (const float*)d_in[3];
  const float* W_ih   = (const float*)d_in[4];
  const float* W_hh   = (const float*)d_in[5];
  const float* b_ih   = (const float*)d_in[6];
  const float* b_hh   = (const float*)d_in[7];
  const float* Wr     = (const float*)d_in[8];
  const float* br     = (const float*)d_in[9];
  const float* W1     = (const float*)d_in[10];
  const float* b1     = (const float*)d_in[11];
  const float* W2     = (const float*)d_in[12];
  const float* b2     = (const float*)d_in[13];
  (void)in_sizes; (void)n_in; (void)out_size; (void)ws_size;

  float* out  = (float*)d_out;                        // [T, DM]
  float* hout = out + (size_t)T_TOK * DM;             // [T, PP]

  char* ws = (char*)d_ws;
  // [0, 32M): W1t bf16 [E][DFF][DM]
  unsigned short* W1t = (unsigned short*)(ws + 0);
  // [32M, 64M): W2t bf16 [E][DM][DFF]
  unsigned short* W2t = (unsigned short*)(ws + 33554432);
  // [64M, 96M): pPart bf16 [4z][2slot][T][DM]; routing temporaries overlap
  // (xp/gx/gh are dead before expert_fused writes pPart)
  unsigned short* pPart = (unsigned short*)(ws + 67108864);
  float* xp = (float*)(ws + 67108864);                // [T,PP]   2MB
  float* gx = (float*)(ws + 69206016);                // [T,3P]   6MB
  float* gh = (float*)(ws + 75497472);                // [T,3P]   6MB
  // [96M, 108M): xg bf16 (12288 rows max)
  unsigned short* xg = (unsigned short*)(ws + 100663296);
  // [108M+): router lists
  float* wgt   = (float*)(ws + 113246208);            // [E,T]
  int* tokslot = (int*)(ws + 113508352);              // [E,T]
  int* cnt     = (int*)(ws + 113770496);              // [E]
  int* offPad  = (int*)(ws + 113770560);              // [E+1]

  zero_cnt<<<1, 64, 0, stream>>>(cnt);

  // weight transpose+convert
  transpose_cvt<<<dim3(DFF/64, DM/64, NE), 256, 0, stream>>>(W1, W1t, DM, DFF);
  transpose_cvt<<<dim3(DM/64, DFF/64, NE), 256, 0, stream>>>(W2, W2t, DFF, DM);

  // routing chain (f32 for exact top-k behavior)
  sgemm_nt_bias<<<dim3(T_TOK/64, PP/64), 256, 0, stream>>>(x, Wp, bp, xp, T_TOK, PP, DM);
  sgemm_nt_bias<<<dim3(T_TOK/64, 384/64), 256, 0, stream>>>(xp, W_ih, b_ih, gx, T_TOK, 384, PP);
  sgemm_nt_bias<<<dim3(T_TOK/64, 384/64), 256, 0, stream>>>(h_prev, W_hh, b_hh, gh, T_TOK, 384, PP);
  gru_elem<<<(T_TOK * PP) / 256, 256, 0, stream>>>(gx, gh, h_prev, hout);
  router_topk<<<T_TOK / 4, 256, 0, stream>>>(hout, Wr, br, wgt, tokslot, cnt);
  calc_off<<<1, 64, 0, stream>>>(cnt, offPad);

  // expert path (fused bf16 MFMA)
  gather_x<<<dim3(32, NE), 256, 0, stream>>>(x, tokslot, cnt, offPad, xg);
  expert_fused<<<dim3(32, NE, 4), 1024, 0, stream>>>(xg, W1t, b1, W2t, b2,
                                                     cnt, offPad, tokslot, wgt, pPart);
  combine_out<<<(T_TOK * DM / 8) / 256, 256, 0, stream>>>(pPart, out);
}

// Round 4
// 731.912 us; speedup vs baseline: 1.4602x; 1.4602x over previous
//
#include <hip/hip_runtime.h>
#include <cmath>

#define T_TOK 4096
#define DM    512
#define DFF   2048
#define NE    16
#define PP    128

typedef __attribute__((ext_vector_type(8))) short bfrag;      // 8 bf16 (4 VGPRs)
typedef __attribute__((ext_vector_type(4))) float f32x4;
typedef __attribute__((ext_vector_type(8))) unsigned short us8;

__device__ __forceinline__ unsigned short f2bf(float f) {
  unsigned int u = __float_as_uint(f);
  unsigned int r = (u + 0x7FFFu + ((u >> 16) & 1u)) >> 16;
  return (unsigned short)r;
}

#define GLOAD_LDS16(g, l) __builtin_amdgcn_global_load_lds( \
    (const __attribute__((address_space(1))) void*)(g), \
    (__attribute__((address_space(3))) void*)(l), 16, 0, 0)

// stage a 128x64 bf16 A-tile and B-tile into LDS (linear dest, inverse-swizzled src)
__device__ __forceinline__ void stage_tile(
    const unsigned short* __restrict__ gA, const unsigned short* __restrict__ gB,
    unsigned short* lA, unsigned short* lB, int t, int ldA, int ldB)
{
  #pragma unroll
  for (int i = 0; i < 4; ++i) {
    int s = t + i * 256; int r = s >> 3, c = s & 7;
    GLOAD_LDS16(gA + (size_t)r * ldA + ((c ^ (r & 7)) << 3), &lA[s * 8]);
  }
  #pragma unroll
  for (int i = 0; i < 4; ++i) {
    int s = t + i * 256; int r = s >> 3, c = s & 7;
    GLOAD_LDS16(gB + (size_t)r * ldB + ((c ^ (r & 7)) << 3), &lB[s * 8]);
  }
}

// ---------------------------------------------------------------------------
// f32 tiled SGEMM: C[M,N] = A[M,K] * B[N,K]^T + bias[N]   (routing chain)
// ---------------------------------------------------------------------------
__global__ __launch_bounds__(256) void sgemm_nt_bias(
    const float* __restrict__ A, const float* __restrict__ B,
    const float* __restrict__ bias, float* __restrict__ C,
    int M, int N, int K)
{
  __shared__ __align__(16) float As[16][68];
  __shared__ __align__(16) float Bs[16][68];
  const int bm = blockIdx.x * 64;
  const int bn = blockIdx.y * 64;
  const int tid = threadIdx.x;
  const int tx = tid & 15;
  const int ty = tid >> 4;

  float acc[4][4] = {{0.f}};

  for (int k0 = 0; k0 < K; k0 += 16) {
    {
      int r  = tid >> 2;
      int c4 = (tid & 3) * 4;
      float4 v = *(const float4*)(A + (size_t)(bm + r) * K + k0 + c4);
      As[c4+0][r] = v.x; As[c4+1][r] = v.y; As[c4+2][r] = v.z; As[c4+3][r] = v.w;
    }
    {
      int r  = tid >> 2;
      int c4 = (tid & 3) * 4;
      float4 v = *(const float4*)(B + (size_t)(bn + r) * K + k0 + c4);
      Bs[c4+0][r] = v.x; Bs[c4+1][r] = v.y; Bs[c4+2][r] = v.z; Bs[c4+3][r] = v.w;
    }
    __syncthreads();
    #pragma unroll
    for (int k = 0; k < 16; ++k) {
      float4 a4 = *(const float4*)&As[k][ty*4];
      float4 b4 = *(const float4*)&Bs[k][tx*4];
      float a[4] = {a4.x, a4.y, a4.z, a4.w};
      float b[4] = {b4.x, b4.y, b4.z, b4.w};
      #pragma unroll
      for (int i = 0; i < 4; ++i)
        #pragma unroll
        for (int j = 0; j < 4; ++j)
          acc[i][j] += a[i] * b[j];
    }
    __syncthreads();
  }
  #pragma unroll
  for (int i = 0; i < 4; ++i) {
    int row = bm + ty*4 + i;
    #pragma unroll
    for (int j = 0; j < 4; ++j) {
      int col = bn + tx*4 + j;
      C[(size_t)row * N + col] = acc[i][j] + bias[col];
    }
  }
}

// ---------------------------------------------------------------------------
// GRU elementwise
// ---------------------------------------------------------------------------
__global__ void gru_elem(const float* __restrict__ gx, const float* __restrict__ gh,
                         const float* __restrict__ hprev, float* __restrict__ hout)
{
  int i = blockIdx.x * blockDim.x + threadIdx.x;
  int t = i >> 7, p = i & 127;
  const float* gxr = gx + (size_t)t * 384;
  const float* ghr = gh + (size_t)t * 384;
  float xr = gxr[p], xz = gxr[128 + p], xn = gxr[256 + p];
  float hr = ghr[p], hz = ghr[128 + p], hn = ghr[256 + p];
  float r = 1.f / (1.f + expf(-(xr + hr)));
  float z = 1.f / (1.f + expf(-(xz + hz)));
  float n = tanhf(xn + r * hn);
  hout[i] = (1.f - z) * n + z * hprev[i];
}

// ---------------------------------------------------------------------------
// Router: softmax -> top-2 (stable) -> renorm -> per-expert lists
// ---------------------------------------------------------------------------
__global__ void router_topk(const float* __restrict__ h, const float* __restrict__ Wr,
                            const float* __restrict__ br,
                            float* __restrict__ wgt, int* __restrict__ tokslot,
                            int* __restrict__ cnt)
{
  int wave = threadIdx.x >> 6;
  int lane = threadIdx.x & 63;
  int t = blockIdx.x * 4 + wave;

  float logit = 0.f;
  if (lane < NE) {
    const float* hr = h + (size_t)t * PP;
    const float* wr = Wr + (size_t)lane * PP;
    float s = 0.f;
    #pragma unroll 8
    for (int p = 0; p < PP; ++p) s += hr[p] * wr[p];
    logit = s + br[lane];
  }
  float l[NE];
  #pragma unroll
  for (int e = 0; e < NE; ++e) l[e] = __shfl(logit, e, 64);

  if (lane == 0) {
    float mx = l[0];
    #pragma unroll
    for (int e = 1; e < NE; ++e) mx = fmaxf(mx, l[e]);
    float p[NE];
    #pragma unroll
    for (int e = 0; e < NE; ++e) p[e] = expf(l[e] - mx);
    int i0 = 0; float m0 = p[0];
    #pragma unroll
    for (int e = 1; e < NE; ++e) { if (p[e] > m0) { m0 = p[e]; i0 = e; } }
    int i1 = -1; float m1 = -1.f;
    #pragma unroll
    for (int e = 0; e < NE; ++e) { if (e != i0 && p[e] > m1) { m1 = p[e]; i1 = e; } }
    float inv = 1.f / (m0 + m1);
    int pos0 = atomicAdd(&cnt[i0], 1);
    tokslot[(size_t)i0 * T_TOK + pos0] = (t << 1);
    wgt[(size_t)i0 * T_TOK + pos0] = m0 * inv;
    int pos1 = atomicAdd(&cnt[i1], 1);
    tokslot[(size_t)i1 * T_TOK + pos1] = (t << 1) | 1;
    wgt[(size_t)i1 * T_TOK + pos1] = m1 * inv;
  }
}

__global__ void zero_cnt(int* cnt) { if (threadIdx.x < NE) cnt[threadIdx.x] = 0; }

__global__ void calc_off(const int* __restrict__ cnt, int* __restrict__ offPad) {
  if (threadIdx.x == 0) {
    int s = 0;
    for (int e = 0; e < NE; ++e) { offPad[e] = s; s += (cnt[e] + 127) & ~127; }
    offPad[NE] = s;
  }
}

// ---------------------------------------------------------------------------
// Transpose+convert: in [E][K][N] f32 -> out [E][N][K] bf16  (64x64 tiles)
// ---------------------------------------------------------------------------
__global__ __launch_bounds__(256) void transpose_cvt(
    const float* __restrict__ in, unsigned short* __restrict__ out, int K, int N)
{
  __shared__ float tl[64][65];
  int e = blockIdx.z, kt = blockIdx.y, nt = blockIdx.x;
  const float* ib = in + (size_t)e * K * N + (size_t)(kt * 64) * N + nt * 64;
  int t = threadIdx.x;
  int r = t >> 2, c0 = (t & 3) * 16;
  #pragma unroll
  for (int i = 0; i < 4; ++i) {
    float4 v = *(const float4*)(ib + (size_t)r * N + c0 + i * 4);
    tl[r][c0+i*4+0] = v.x; tl[r][c0+i*4+1] = v.y;
    tl[r][c0+i*4+2] = v.z; tl[r][c0+i*4+3] = v.w;
  }
  __syncthreads();
  unsigned short* ob = out + (size_t)e * N * K + (size_t)(nt * 64) * K + kt * 64;
  #pragma unroll
  for (int i = 0; i < 2; ++i) {
    int u = t + i * 256;
    int n = u >> 3, k0 = (u & 7) * 8;
    us8 o;
    #pragma unroll
    for (int j = 0; j < 8; ++j) o[j] = f2bf(tl[k0 + j][n]);
    *(us8*)(ob + (size_t)n * K + k0) = o;
  }
}

// ---------------------------------------------------------------------------
// Gather routed tokens -> compact padded bf16 xg [rows][DM]
// ---------------------------------------------------------------------------
__global__ __launch_bounds__(256) void gather_x(
    const float* __restrict__ x, const int* __restrict__ tokslot,
    const int* __restrict__ cnt, const int* __restrict__ offPad,
    unsigned short* __restrict__ xg)
{
  int e = blockIdx.y;
  int n = cnt[e];
  int npad = (n + 127) & ~127;
  int r0 = blockIdx.x * 128;
  if (r0 >= npad) return;
  int t = threadIdx.x;
  int r = r0 + (t >> 1);
  int half = t & 1;
  unsigned short* orow = xg + (size_t)(offPad[e] + r) * DM + half * 256;
  if (r >= n) {
    us8 z = {0,0,0,0,0,0,0,0};
    #pragma unroll
    for (int i = 0; i < 32; ++i) *(us8*)(orow + i * 8) = z;
    return;
  }
  int tok = tokslot[(size_t)e * T_TOK + r] >> 1;
  const float* irow = x + (size_t)tok * DM + half * 256;
  #pragma unroll
  for (int i = 0; i < 32; ++i) {
    float4 a = *(const float4*)(irow + i * 8);
    float4 b = *(const float4*)(irow + i * 8 + 4);
    us8 o;
    o[0]=f2bf(a.x); o[1]=f2bf(a.y); o[2]=f2bf(a.z); o[3]=f2bf(a.w);
    o[4]=f2bf(b.x); o[5]=f2bf(b.y); o[6]=f2bf(b.z); o[7]=f2bf(b.w);
    *(us8*)(orow + i * 8) = o;
  }
}

// ---------------------------------------------------------------------------
// GEMM1: hidden = relu(xg @ W1t^T + b1)  -- 128x128 tile, BK=64, 4 waves,
// double-buffered LDS + counted vmcnt (2-phase pipeline)
// ---------------------------------------------------------------------------
__global__ __launch_bounds__(256) void expert_gemm1(
    const unsigned short* __restrict__ xg, const unsigned short* __restrict__ W1t,
    const float* __restrict__ b1,
    const int* __restrict__ cnt, const int* __restrict__ offPad,
    unsigned short* __restrict__ hidden)
{
  int e = blockIdx.y;
  int npad = (cnt[e] + 127) & ~127;
  int tile = blockIdx.x;
  if (tile * 128 >= npad) return;
  int nb = blockIdx.z * 128;

  __shared__ unsigned short xs[2][128 * 64];
  __shared__ unsigned short ws1[2][128 * 64];

  int t = threadIdx.x, lane = t & 63, wv = t >> 6;
  int l15 = lane & 15, lg = lane >> 4;
  int wm = (wv & 1) * 64, wn = (wv >> 1) * 64;

  int base = offPad[e] + tile * 128;
  const unsigned short* xgb = xg + (size_t)base * DM;
  const unsigned short* w1b = W1t + ((size_t)e * DFF + nb) * DM;

  f32x4 acc[4][4];
  #pragma unroll
  for (int i = 0; i < 4; ++i)
    #pragma unroll
    for (int j = 0; j < 4; ++j) acc[i][j] = (f32x4){0.f, 0.f, 0.f, 0.f};

  stage_tile(xgb, w1b, xs[0], ws1[0], t, DM, DM);

  for (int kt = 0; kt < 8; ++kt) {
    int cur = kt & 1;
    if (kt < 7) {
      stage_tile(xgb + (kt + 1) * 64, w1b + (kt + 1) * 64, xs[cur ^ 1], ws1[cur ^ 1], t, DM, DM);
      asm volatile("s_waitcnt vmcnt(8)" ::: "memory");
    } else {
      asm volatile("s_waitcnt vmcnt(0)" ::: "memory");
    }
    __builtin_amdgcn_s_barrier();
    asm volatile("" ::: "memory");

    #pragma unroll
    for (int kk = 0; kk < 2; ++kk) {
      int cidx = kk * 4 + lg;
      bfrag a[4], b[4];
      #pragma unroll
      for (int fi = 0; fi < 4; ++fi) {
        int row = wm + fi * 16 + l15;
        a[fi] = *(const bfrag*)&xs[cur][row * 64 + ((cidx ^ (row & 7)) << 3)];
      }
      #pragma unroll
      for (int fj = 0; fj < 4; ++fj) {
        int row = wn + fj * 16 + l15;
        b[fj] = *(const bfrag*)&ws1[cur][row * 64 + ((cidx ^ (row & 7)) << 3)];
      }
      #pragma unroll
      for (int fi = 0; fi < 4; ++fi)
        #pragma unroll
        for (int fj = 0; fj < 4; ++fj)
          acc[fi][fj] = __builtin_amdgcn_mfma_f32_16x16x32_bf16(a[fi], b[fj], acc[fi][fj], 0, 0, 0);
    }
    asm volatile("s_waitcnt lgkmcnt(0)" ::: "memory");
    __builtin_amdgcn_s_barrier();
    asm volatile("" ::: "memory");
  }

  unsigned short* hb = hidden + (size_t)base * DFF + nb;
  #pragma unroll
  for (int fj = 0; fj < 4; ++fj) {
    int col = wn + fj * 16 + l15;
    float bias = b1[(size_t)e * DFF + nb + col];
    #pragma unroll
    for (int fi = 0; fi < 4; ++fi) {
      #pragma unroll
      for (int rg = 0; rg < 4; ++rg) {
        int row = wm + fi * 16 + lg * 4 + rg;
        float v = acc[fi][fj][rg] + bias;
        hb[(size_t)row * DFF + col] = f2bf(v > 0.f ? v : 0.f);
      }
    }
  }
}

// ---------------------------------------------------------------------------
// GEMM2: y = hidden @ W2t^T (+b2 on khalf 0), scaled scatter to f32 planes.
// 128x128 tile, BK=64, 4 waves, split-K x2, double-buffered + counted vmcnt
// ---------------------------------------------------------------------------
__global__ __launch_bounds__(256) void expert_gemm2(
    const unsigned short* __restrict__ hidden, const unsigned short* __restrict__ W2t,
    const float* __restrict__ b2,
    const int* __restrict__ cnt, const int* __restrict__ offPad,
    const int* __restrict__ tokslot, const float* __restrict__ wgt,
    float* __restrict__ planes)
{
  int e = blockIdx.y;
  int n = cnt[e];
  int npad = (n + 127) & ~127;
  int tile = blockIdx.x;
  if (tile * 128 >= npad) return;
  int nt    = blockIdx.z & 3;
  int khalf = blockIdx.z >> 2;
  int nb = nt * 128;
  int kbase = khalf * 1024;

  __shared__ unsigned short hs[2][128 * 64];
  __shared__ unsigned short ws2[2][128 * 64];
  __shared__ int   ltok[128];
  __shared__ float lw[128];

  int t = threadIdx.x, lane = t & 63, wv = t >> 6;
  int l15 = lane & 15, lg = lane >> 4;
  int wm = (wv & 1) * 64, wn = (wv >> 1) * 64;

  if (t < 128) {
    int idx = tile * 128 + t;
    if (idx < n) {
      ltok[t] = tokslot[(size_t)e * T_TOK + idx];
      lw[t]   = wgt[(size_t)e * T_TOK + idx];
    } else { ltok[t] = -1; lw[t] = 0.f; }
  }

  int base = offPad[e] + tile * 128;
  const unsigned short* hbb = hidden + (size_t)base * DFF + kbase;
  const unsigned short* w2b = W2t + ((size_t)e * DM + nb) * DFF + kbase;

  f32x4 acc[4][4];
  #pragma unroll
  for (int i = 0; i < 4; ++i)
    #pragma unroll
    for (int j = 0; j < 4; ++j) acc[i][j] = (f32x4){0.f, 0.f, 0.f, 0.f};

  stage_tile(hbb, w2b, hs[0], ws2[0], t, DFF, DFF);

  for (int kt = 0; kt < 16; ++kt) {
    int cur = kt & 1;
    if (kt < 15) {
      stage_tile(hbb + (kt + 1) * 64, w2b + (kt + 1) * 64, hs[cur ^ 1], ws2[cur ^ 1], t, DFF, DFF);
      asm volatile("s_waitcnt vmcnt(8)" ::: "memory");
    } else {
      asm volatile("s_waitcnt vmcnt(0)" ::: "memory");
    }
    __builtin_amdgcn_s_barrier();
    asm volatile("" ::: "memory");

    #pragma unroll
    for (int kk = 0; kk < 2; ++kk) {
      int cidx = kk * 4 + lg;
      bfrag a[4], b[4];
      #pragma unroll
      for (int fi = 0; fi < 4; ++fi) {
        int row = wm + fi * 16 + l15;
        a[fi] = *(const bfrag*)&hs[cur][row * 64 + ((cidx ^ (row & 7)) << 3)];
      }
      #pragma unroll
      for (int fj = 0; fj < 4; ++fj) {
        int row = wn + fj * 16 + l15;
        b[fj] = *(const bfrag*)&ws2[cur][row * 64 + ((cidx ^ (row & 7)) << 3)];
      }
      #pragma unroll
      for (int fi = 0; fi < 4; ++fi)
        #pragma unroll
        for (int fj = 0; fj < 4; ++fj)
          acc[fi][fj] = __builtin_amdgcn_mfma_f32_16x16x32_bf16(a[fi], b[fj], acc[fi][fj], 0, 0, 0);
    }
    asm volatile("s_waitcnt lgkmcnt(0)" ::: "memory");
    __builtin_amdgcn_s_barrier();
    asm volatile("" ::: "memory");
  }

  #pragma unroll
  for (int fj = 0; fj < 4; ++fj) {
    int col = wn + fj * 16 + l15;
    int gcol = nb + col;
    float bv = (khalf == 0) ? b2[(size_t)e * DM + gcol] : 0.f;
    #pragma unroll
    for (int fi = 0; fi < 4; ++fi) {
      #pragma unroll
      for (int rg = 0; rg < 4; ++rg) {
        int r = wm + fi * 16 + lg * 4 + rg;
        int ts = ltok[r];
        if (ts < 0) continue;
        float v = (acc[fi][fj][rg] + bv) * lw[r];
        planes[((size_t)(khalf * 2 + (ts & 1)) * T_TOK + (ts >> 1)) * DM + gcol] = v;
      }
    }
  }
}

// ---------------------------------------------------------------------------
// Combine: out = sum of 4 f32 planes
// ---------------------------------------------------------------------------
__global__ __launch_bounds__(256) void combine_out(
    const float4* __restrict__ p, float4* __restrict__ out)
{
  int i = blockIdx.x * blockDim.x + threadIdx.x;   // i < T*DM/4
  const int PS = T_TOK * DM / 4;
  float4 a = p[i], b = p[i + PS], c = p[i + 2 * PS], d = p[i + 3 * PS];
  out[i] = make_float4(a.x + b.x + c.x + d.x, a.y + b.y + c.y + d.y,
                       a.z + b.z + c.z + d.z, a.w + b.w + c.w + d.w);
}

// ---------------------------------------------------------------------------
extern "C" void kernel_launch(void* const* d_in, const int* in_sizes, int n_in,
                              void* d_out, int out_size, void* d_ws, size_t ws_size,
                              hipStream_t stream)
{
  const float* x      = (const float*)d_in[0];
  const float* h_prev = (const float*)d_in[1];
  const float* Wp     = (const float*)d_in[2];
  const float* bp     = (const float*)d_in[3];
  const float* W_ih   = (const float*)d_in[4];
  const float* W_hh   = (const float*)d_in[5];
  const float* b_ih   = (const float*)d_in[6];
  const float* b_hh   = (const float*)d_in[7];
  const float* Wr     = (const float*)d_in[8];
  const float* br     = (const float*)d_in[9];
  const float* W1     = (const float*)d_in[10];
  const float* b1     = (const float*)d_in[11];
  const float* W2     = (const float*)d_in[12];
  const float* b2     = (const float*)d_in[13];
  (void)in_sizes; (void)n_in; (void)out_size; (void)ws_size;

  float* out  = (float*)d_out;                        // [T, DM]
  float* hout = out + (size_t)T_TOK * DM;             // [T, PP]

  char* ws = (char*)d_ws;
  // [0, 32M): W1t bf16 (consumed by gemm1) -> then reused as 4 f32 planes (gemm2)
  unsigned short* W1t = (unsigned short*)(ws + 0);
  float* planes = (float*)(ws + 0);                   // 4 x [T][DM] f32 = 32M
  // [32M, 64M): W2t bf16
  unsigned short* W2t = (unsigned short*)(ws + 33554432);
  // [64M, 104M): hidden bf16 (10240 rows x 2048); routing temps overlap (dead first)
  unsigned short* hidden = (unsigned short*)(ws + 67108864);
  float* xp = (float*)(ws + 67108864);                // [T,PP]   2MB
  float* gx = (float*)(ws + 69206016);                // [T,3P]   6MB
  float* gh = (float*)(ws + 75497472);                // [T,3P]   6MB
  // [104M, 114M): xg bf16 (10240 rows x 512)
  unsigned short* xg = (unsigned short*)(ws + 109051904);
  // [114M+): router lists
  float* wgt   = (float*)(ws + 119537664);            // [E,T]
  int* tokslot = (int*)(ws + 119799808);              // [E,T]
  int* cnt     = (int*)(ws + 120061952);              // [E]
  int* offPad  = (int*)(ws + 120062016);              // [E+1]

  zero_cnt<<<1, 64, 0, stream>>>(cnt);

  // routing chain (f32 for exact top-k behavior) -- uses temps in hidden region
  sgemm_nt_bias<<<dim3(T_TOK/64, PP/64), 256, 0, stream>>>(x, Wp, bp, xp, T_TOK, PP, DM);
  sgemm_nt_bias<<<dim3(T_TOK/64, 384/64), 256, 0, stream>>>(xp, W_ih, b_ih, gx, T_TOK, 384, PP);
  sgemm_nt_bias<<<dim3(T_TOK/64, 384/64), 256, 0, stream>>>(h_prev, W_hh, b_hh, gh, T_TOK, 384, PP);
  gru_elem<<<(T_TOK * PP) / 256, 256, 0, stream>>>(gx, gh, h_prev, hout);
  router_topk<<<T_TOK / 4, 256, 0, stream>>>(hout, Wr, br, wgt, tokslot, cnt);
  calc_off<<<1, 64, 0, stream>>>(cnt, offPad);

  // weight transpose+convert (after routing temps are dead where overlapping)
  transpose_cvt<<<dim3(DFF/64, DM/64, NE), 256, 0, stream>>>(W1, W1t, DM, DFF);
  transpose_cvt<<<dim3(DM/64, DFF/64, NE), 256, 0, stream>>>(W2, W2t, DFF, DM);

  // expert path (bf16 MFMA, 2-phase pipelined)
  gather_x<<<dim3(32, NE), 256, 0, stream>>>(x, tokslot, cnt, offPad, xg);
  expert_gemm1<<<dim3(32, NE, DFF/128), 256, 0, stream>>>(xg, W1t, b1, cnt, offPad, hidden);
  expert_gemm2<<<dim3(32, NE, 8), 256, 0, stream>>>(hidden, W2t, b2, cnt, offPad,
                                                    tokslot, wgt, planes);
  combine_out<<<(T_TOK * DM / 4) / 256, 256, 0, stream>>>((const float4*)planes, (float4*)out);
}

// Round 5
// 372.208 us; speedup vs baseline: 2.8714x; 1.9664x over previous
//
#include <hip/hip_runtime.h>
#include <cmath>

#define T_TOK 4096
#define DM    512
#define DFF   2048
#define NE    16
#define PP    128

typedef __attribute__((ext_vector_type(8))) short bfrag;      // 8 bf16 (4 VGPRs)
typedef __attribute__((ext_vector_type(4))) float f32x4;
typedef __attribute__((ext_vector_type(8))) unsigned short us8;

__device__ __forceinline__ unsigned short f2bf(float f) {
  unsigned int u = __float_as_uint(f);
  unsigned int r = (u + 0x7FFFu + ((u >> 16) & 1u)) >> 16;
  return (unsigned short)r;
}
__device__ __forceinline__ float bf2f(unsigned short b) {
  return __uint_as_float(((unsigned int)b) << 16);
}

#define GLOAD_LDS16(g, l) __builtin_amdgcn_global_load_lds( \
    (const __attribute__((address_space(1))) void*)(g), \
    (__attribute__((address_space(3))) void*)(l), 16, 0, 0)

// ---------------------------------------------------------------------------
// f32 tiled SGEMM: C[M,N] = A[M,K] * B[N,K]^T + bias[N]   (routing chain)
// ---------------------------------------------------------------------------
__global__ __launch_bounds__(256) void sgemm_nt_bias(
    const float* __restrict__ A, const float* __restrict__ B,
    const float* __restrict__ bias, float* __restrict__ C,
    int M, int N, int K)
{
  __shared__ __align__(16) float As[16][68];
  __shared__ __align__(16) float Bs[16][68];
  const int bm = blockIdx.x * 64;
  const int bn = blockIdx.y * 64;
  const int tid = threadIdx.x;
  const int tx = tid & 15;
  const int ty = tid >> 4;

  float acc[4][4] = {{0.f}};

  for (int k0 = 0; k0 < K; k0 += 16) {
    {
      int r  = tid >> 2;
      int c4 = (tid & 3) * 4;
      float4 v = *(const float4*)(A + (size_t)(bm + r) * K + k0 + c4);
      As[c4+0][r] = v.x; As[c4+1][r] = v.y; As[c4+2][r] = v.z; As[c4+3][r] = v.w;
    }
    {
      int r  = tid >> 2;
      int c4 = (tid & 3) * 4;
      float4 v = *(const float4*)(B + (size_t)(bn + r) * K + k0 + c4);
      Bs[c4+0][r] = v.x; Bs[c4+1][r] = v.y; Bs[c4+2][r] = v.z; Bs[c4+3][r] = v.w;
    }
    __syncthreads();
    #pragma unroll
    for (int k = 0; k < 16; ++k) {
      float4 a4 = *(const float4*)&As[k][ty*4];
      float4 b4 = *(const float4*)&Bs[k][tx*4];
      float a[4] = {a4.x, a4.y, a4.z, a4.w};
      float b[4] = {b4.x, b4.y, b4.z, b4.w};
      #pragma unroll
      for (int i = 0; i < 4; ++i)
        #pragma unroll
        for (int j = 0; j < 4; ++j)
          acc[i][j] += a[i] * b[j];
    }
    __syncthreads();
  }
  #pragma unroll
  for (int i = 0; i < 4; ++i) {
    int row = bm + ty*4 + i;
    #pragma unroll
    for (int j = 0; j < 4; ++j) {
      int col = bn + tx*4 + j;
      C[(size_t)row * N + col] = acc[i][j] + bias[col];
    }
  }
}

// ---------------------------------------------------------------------------
// Fused gate GEMM: C[T,512] = [xp | h_prev] @ Bcat^T + bcat   (K = 256)
// cols 0-255: xr+hr, xz+hz (summed in-GEMM); 256-383: xn; 384-511: hn
// ---------------------------------------------------------------------------
__global__ __launch_bounds__(256) void sgemm_cat(
    const float* __restrict__ A1, const float* __restrict__ A2,
    const float* __restrict__ B, const float* __restrict__ bias,
    float* __restrict__ C)
{
  __shared__ __align__(16) float As[16][68];
  __shared__ __align__(16) float Bs[16][68];
  const int bm = blockIdx.x * 64;
  const int bn = blockIdx.y * 64;
  const int tid = threadIdx.x;
  const int tx = tid & 15;
  const int ty = tid >> 4;

  float acc[4][4] = {{0.f}};

  for (int k0 = 0; k0 < 256; k0 += 16) {
    {
      int r  = tid >> 2;
      int c4 = (tid & 3) * 4;
      const float* src = (k0 < 128) ? (A1 + (size_t)(bm + r) * 128 + k0 + c4)
                                    : (A2 + (size_t)(bm + r) * 128 + (k0 - 128) + c4);
      float4 v = *(const float4*)src;
      As[c4+0][r] = v.x; As[c4+1][r] = v.y; As[c4+2][r] = v.z; As[c4+3][r] = v.w;
    }
    {
      int r  = tid >> 2;
      int c4 = (tid & 3) * 4;
      float4 v = *(const float4*)(B + (size_t)(bn + r) * 256 + k0 + c4);
      Bs[c4+0][r] = v.x; Bs[c4+1][r] = v.y; Bs[c4+2][r] = v.z; Bs[c4+3][r] = v.w;
    }
    __syncthreads();
    #pragma unroll
    for (int k = 0; k < 16; ++k) {
      float4 a4 = *(const float4*)&As[k][ty*4];
      float4 b4 = *(const float4*)&Bs[k][tx*4];
      float a[4] = {a4.x, a4.y, a4.z, a4.w};
      float b[4] = {b4.x, b4.y, b4.z, b4.w};
      #pragma unroll
      for (int i = 0; i < 4; ++i)
        #pragma unroll
        for (int j = 0; j < 4; ++j)
          acc[i][j] += a[i] * b[j];
    }
    __syncthreads();
  }
  #pragma unroll
  for (int i = 0; i < 4; ++i) {
    int row = bm + ty*4 + i;
    #pragma unroll
    for (int j = 0; j < 4; ++j) {
      int col = bn + tx*4 + j;
      C[(size_t)row * 512 + col] = acc[i][j] + bias[col];
    }
  }
}

// build Bcat [512][256] and bcat [512]
__global__ void prep_gates(const float* __restrict__ W_ih, const float* __restrict__ W_hh,
                           const float* __restrict__ b_ih, const float* __restrict__ b_hh,
                           float* __restrict__ Bcat, float* __restrict__ bcat)
{
  int id = blockIdx.x * 256 + threadIdx.x;   // 131072
  int n = id >> 8, k = id & 255;
  float v;
  if (n < 256)      v = (k < 128) ? W_ih[n * 128 + k] : W_hh[n * 128 + k - 128];
  else if (n < 384) v = (k < 128) ? W_ih[n * 128 + k] : 0.f;
  else              v = (k < 128) ? 0.f : W_hh[(n - 128) * 128 + k - 128];
  Bcat[n * 256 + k] = v;
  if (id < 512) {
    float b = (id < 256) ? (b_ih[id] + b_hh[id])
            : (id < 384) ? b_ih[id] : b_hh[id - 128];
    bcat[id] = b;
  }
}

// ---------------------------------------------------------------------------
// GRU elementwise from fused gate buffer s[T,512]
// ---------------------------------------------------------------------------
__global__ void gru_elem2(const float* __restrict__ s, const float* __restrict__ hprev,
                          float* __restrict__ hout)
{
  int i = blockIdx.x * blockDim.x + threadIdx.x;
  int t = i >> 7, p = i & 127;
  const float* sr = s + (size_t)t * 512;
  float rz = sr[p], zz = sr[128 + p], xn = sr[256 + p], hn = sr[384 + p];
  float r = 1.f / (1.f + expf(-rz));
  float z = 1.f / (1.f + expf(-zz));
  float n = tanhf(xn + r * hn);
  hout[i] = (1.f - z) * n + z * hprev[i];
}

// ---------------------------------------------------------------------------
// Router: softmax -> top-2 (stable) -> renorm -> per-expert lists
// ---------------------------------------------------------------------------
__global__ void router_topk(const float* __restrict__ h, const float* __restrict__ Wr,
                            const float* __restrict__ br,
                            float* __restrict__ wgt, int* __restrict__ tokslot,
                            int* __restrict__ cnt)
{
  int wave = threadIdx.x >> 6;
  int lane = threadIdx.x & 63;
  int t = blockIdx.x * 4 + wave;

  float logit = 0.f;
  if (lane < NE) {
    const float* hr = h + (size_t)t * PP;
    const float* wr = Wr + (size_t)lane * PP;
    float s = 0.f;
    #pragma unroll 8
    for (int p = 0; p < PP; ++p) s += hr[p] * wr[p];
    logit = s + br[lane];
  }
  float l[NE];
  #pragma unroll
  for (int e = 0; e < NE; ++e) l[e] = __shfl(logit, e, 64);

  if (lane == 0) {
    float mx = l[0];
    #pragma unroll
    for (int e = 1; e < NE; ++e) mx = fmaxf(mx, l[e]);
    float p[NE];
    #pragma unroll
    for (int e = 0; e < NE; ++e) p[e] = expf(l[e] - mx);
    int i0 = 0; float m0 = p[0];
    #pragma unroll
    for (int e = 1; e < NE; ++e) { if (p[e] > m0) { m0 = p[e]; i0 = e; } }
    int i1 = -1; float m1 = -1.f;
    #pragma unroll
    for (int e = 0; e < NE; ++e) { if (e != i0 && p[e] > m1) { m1 = p[e]; i1 = e; } }
    float inv = 1.f / (m0 + m1);
    int pos0 = atomicAdd(&cnt[i0], 1);
    tokslot[(size_t)i0 * T_TOK + pos0] = (t << 1);
    wgt[(size_t)i0 * T_TOK + pos0] = m0 * inv;
    int pos1 = atomicAdd(&cnt[i1], 1);
    tokslot[(size_t)i1 * T_TOK + pos1] = (t << 1) | 1;
    wgt[(size_t)i1 * T_TOK + pos1] = m1 * inv;
  }
}

__global__ void zero_cnt(int* cnt) { if (threadIdx.x < NE) cnt[threadIdx.x] = 0; }

__global__ void calc_off(const int* __restrict__ cnt, int* __restrict__ offPad) {
  if (threadIdx.x == 0) {
    int s = 0;
    for (int e = 0; e < NE; ++e) { offPad[e] = s; s += (cnt[e] + 127) & ~127; }
    offPad[NE] = s;
  }
}

// ---------------------------------------------------------------------------
// Transpose+convert: in [E][K][N] f32 -> out [E][N][K] bf16  (64x64 tiles)
// ---------------------------------------------------------------------------
__global__ __launch_bounds__(256) void transpose_cvt(
    const float* __restrict__ in, unsigned short* __restrict__ out, int K, int N)
{
  __shared__ float tl[64][65];
  int e = blockIdx.z, kt = blockIdx.y, nt = blockIdx.x;
  const float* ib = in + (size_t)e * K * N + (size_t)(kt * 64) * N + nt * 64;
  int t = threadIdx.x;
  int r = t >> 2, c0 = (t & 3) * 16;
  #pragma unroll
  for (int i = 0; i < 4; ++i) {
    float4 v = *(const float4*)(ib + (size_t)r * N + c0 + i * 4);
    tl[r][c0+i*4+0] = v.x; tl[r][c0+i*4+1] = v.y;
    tl[r][c0+i*4+2] = v.z; tl[r][c0+i*4+3] = v.w;
  }
  __syncthreads();
  unsigned short* ob = out + (size_t)e * N * K + (size_t)(nt * 64) * K + kt * 64;
  #pragma unroll
  for (int i = 0; i < 2; ++i) {
    int u = t + i * 256;
    int n = u >> 3, k0 = (u & 7) * 8;
    us8 o;
    #pragma unroll
    for (int j = 0; j < 8; ++j) o[j] = f2bf(tl[k0 + j][n]);
    *(us8*)(ob + (size_t)n * K + k0) = o;
  }
}

// ---------------------------------------------------------------------------
// Gather routed tokens -> compact padded bf16 xg [rows][DM]
// ---------------------------------------------------------------------------
__global__ __launch_bounds__(256) void gather_x(
    const float* __restrict__ x, const int* __restrict__ tokslot,
    const int* __restrict__ cnt, const int* __restrict__ offPad,
    unsigned short* __restrict__ xg)
{
  int e = blockIdx.y;
  int n = cnt[e];
  int npad = (n + 127) & ~127;
  int r0 = blockIdx.x * 128;
  if (r0 >= npad) return;
  int t = threadIdx.x;
  int r = r0 + (t >> 1);
  int half = t & 1;
  unsigned short* orow = xg + (size_t)(offPad[e] + r) * DM + half * 256;
  if (r >= n) {
    us8 z = {0,0,0,0,0,0,0,0};
    #pragma unroll
    for (int i = 0; i < 32; ++i) *(us8*)(orow + i * 8) = z;
    return;
  }
  int tok = tokslot[(size_t)e * T_TOK + r] >> 1;
  const float* irow = x + (size_t)tok * DM + half * 256;
  #pragma unroll
  for (int i = 0; i < 32; ++i) {
    float4 a = *(const float4*)(irow + i * 8);
    float4 b = *(const float4*)(irow + i * 8 + 4);
    us8 o;
    o[0]=f2bf(a.x); o[1]=f2bf(a.y); o[2]=f2bf(a.z); o[3]=f2bf(a.w);
    o[4]=f2bf(b.x); o[5]=f2bf(b.y); o[6]=f2bf(b.z); o[7]=f2bf(b.w);
    *(us8*)(orow + i * 8) = o;
  }
}

// ---------------------------------------------------------------------------
// GEMM1: hidden = relu(xg @ W1t^T + b1)
// Block = (expert, 64-wide ff chunk). W slice [64][512] resident in LDS;
// activations read fragment-wise straight from global (L2). No inner barriers.
// 512 blocks, XCD-swizzled (2 experts per XCD -> L2-resident activations).
// ---------------------------------------------------------------------------
__global__ __launch_bounds__(256) void expert_gemm1(
    const unsigned short* __restrict__ xg, const unsigned short* __restrict__ W1t,
    const float* __restrict__ b1,
    const int* __restrict__ cnt, const int* __restrict__ offPad,
    unsigned short* __restrict__ hidden)
{
  __shared__ unsigned short wlds[64 * 512];   // 64 KB, row stride 1024 B
  int bid = blockIdx.x;
  int xcd = bid & 7, j = bid >> 3;
  int e  = xcd * 2 + (j >> 5);
  int nb = (j & 31) * 64;
  int t = threadIdx.x, lane = t & 63, wv = t >> 6;
  int l15 = lane & 15, lg = lane >> 4;

  // load W slice once (source pre-swizzled so swizzled LDS reads are linear-free)
  const unsigned short* w1b = W1t + ((size_t)e * DFF + nb) * DM;
  #pragma unroll
  for (int i = 0; i < 16; ++i) {
    int s = t + i * 256;                 // 0..4095 16B slots
    int r = s >> 6, c = s & 63;
    int cs = (c & 56) | ((c & 7) ^ (r & 7));
    GLOAD_LDS16(w1b + (size_t)r * DM + (cs << 3), &wlds[s * 8]);
  }
  __syncthreads();

  int npad = (cnt[e] + 127) & ~127;
  int ntiles = npad >> 7;
  int wm = wv * 32;
  int ebase = offPad[e];

  for (int tile = 0; tile < ntiles; ++tile) {
    int rbase = ebase + tile * 128 + wm;
    f32x4 acc[2][4];
    #pragma unroll
    for (int i = 0; i < 2; ++i)
      #pragma unroll
      for (int jj = 0; jj < 4; ++jj) acc[i][jj] = (f32x4){0.f, 0.f, 0.f, 0.f};

    #pragma unroll 2
    for (int kt = 0; kt < 8; ++kt) {
      #pragma unroll
      for (int kk = 0; kk < 2; ++kk) {
        int cidx = kt * 8 + kk * 4 + lg;         // 16B chunk index in [0,64)
        bfrag a[2], b[4];
        #pragma unroll
        for (int fi = 0; fi < 2; ++fi)
          a[fi] = *(const bfrag*)(xg + (size_t)(rbase + fi * 16 + l15) * DM + (cidx << 3));
        #pragma unroll
        for (int fj = 0; fj < 4; ++fj) {
          int row = fj * 16 + l15;
          int cs = (cidx & 56) | ((cidx & 7) ^ (row & 7));
          b[fj] = *(const bfrag*)&wlds[row * 512 + (cs << 3)];
        }
        #pragma unroll
        for (int fi = 0; fi < 2; ++fi)
          #pragma unroll
          for (int fj = 0; fj < 4; ++fj)
            acc[fi][fj] = __builtin_amdgcn_mfma_f32_16x16x32_bf16(a[fi], b[fj], acc[fi][fj], 0, 0, 0);
      }
    }

    #pragma unroll
    for (int fj = 0; fj < 4; ++fj) {
      int col = nb + fj * 16 + l15;
      float bias = b1[(size_t)e * DFF + col];
      #pragma unroll
      for (int fi = 0; fi < 2; ++fi) {
        #pragma unroll
        for (int rg = 0; rg < 4; ++rg) {
          int row = ebase + tile * 128 + wm + fi * 16 + lg * 4 + rg;
          float v = acc[fi][fj][rg] + bias;
          hidden[(size_t)row * DFF + col] = f2bf(v > 0.f ? v : 0.f);
        }
      }
    }
  }
}

// ---------------------------------------------------------------------------
// GEMM2: y = hidden @ W2t^T (+ b2 on kq==0), split-K x4, scaled scatter to
// 8 bf16 planes [kq*2+slot][T][DM]. Same W-resident structure as GEMM1.
// ---------------------------------------------------------------------------
__global__ __launch_bounds__(256) void expert_gemm2(
    const unsigned short* __restrict__ hidden, const unsigned short* __restrict__ W2t,
    const float* __restrict__ b2,
    const int* __restrict__ cnt, const int* __restrict__ offPad,
    const int* __restrict__ tokslot, const float* __restrict__ wgt,
    unsigned short* __restrict__ planes)
{
  __shared__ unsigned short wlds[64 * 512];   // 64 KB
  int bid = blockIdx.x;
  int xcd = bid & 7, j = bid >> 3;
  int e   = xcd * 2 + (j >> 5);
  int r5  = j & 31;
  int ncb = (r5 & 7) * 64;                    // dm chunk base
  int kq  = r5 >> 3;                          // K quarter
  int kb  = kq * 512;
  int t = threadIdx.x, lane = t & 63, wv = t >> 6;
  int l15 = lane & 15, lg = lane >> 4;

  const unsigned short* w2b = W2t + ((size_t)e * DM + ncb) * DFF + kb;
  #pragma unroll
  for (int i = 0; i < 16; ++i) {
    int s = t + i * 256;
    int r = s >> 6, c = s & 63;
    int cs = (c & 56) | ((c & 7) ^ (r & 7));
    GLOAD_LDS16(w2b + (size_t)r * DFF + (cs << 3), &wlds[s * 8]);
  }
  __syncthreads();

  int n = cnt[e];
  int npad = (n + 127) & ~127;
  int ntiles = npad >> 7;
  int wm = wv * 32;
  int ebase = offPad[e];

  for (int tile = 0; tile < ntiles; ++tile) {
    int rbase = ebase + tile * 128 + wm;
    f32x4 acc[2][4];
    #pragma unroll
    for (int i = 0; i < 2; ++i)
      #pragma unroll
      for (int jj = 0; jj < 4; ++jj) acc[i][jj] = (f32x4){0.f, 0.f, 0.f, 0.f};

    #pragma unroll 2
    for (int kt = 0; kt < 8; ++kt) {
      #pragma unroll
      for (int kk = 0; kk < 2; ++kk) {
        int cidx = kt * 8 + kk * 4 + lg;
        bfrag a[2], b[4];
        #pragma unroll
        for (int fi = 0; fi < 2; ++fi)
          a[fi] = *(const bfrag*)(hidden + (size_t)(rbase + fi * 16 + l15) * DFF + kb + (cidx << 3));
        #pragma unroll
        for (int fj = 0; fj < 4; ++fj) {
          int row = fj * 16 + l15;
          int cs = (cidx & 56) | ((cidx & 7) ^ (row & 7));
          b[fj] = *(const bfrag*)&wlds[row * 512 + (cs << 3)];
        }
        #pragma unroll
        for (int fi = 0; fi < 2; ++fi)
          #pragma unroll
          for (int fj = 0; fj < 4; ++fj)
            acc[fi][fj] = __builtin_amdgcn_mfma_f32_16x16x32_bf16(a[fi], b[fj], acc[fi][fj], 0, 0, 0);
      }
    }

    // epilogue: per-row token/weight, write to plane kq*2+slot
    #pragma unroll
    for (int fi = 0; fi < 2; ++fi) {
      #pragma unroll
      for (int rg = 0; rg < 4; ++rg) {
        int lrow = wm + fi * 16 + lg * 4 + rg;
        int idx = tile * 128 + lrow;
        if (idx >= n) continue;
        int ts = tokslot[(size_t)e * T_TOK + idx];
        float w = wgt[(size_t)e * T_TOK + idx];
        unsigned short* pl = planes + ((size_t)(kq * 2 + (ts & 1)) * T_TOK + (ts >> 1)) * DM;
        #pragma unroll
        for (int fj = 0; fj < 4; ++fj) {
          int col = ncb + fj * 16 + l15;
          float bv = (kq == 0) ? b2[(size_t)e * DM + col] : 0.f;
          pl[col] = f2bf((acc[fi][fj][rg] + bv) * w);
        }
      }
    }
  }
}

// ---------------------------------------------------------------------------
// Combine: out[t][d] = sum over 8 bf16 planes
// ---------------------------------------------------------------------------
__global__ __launch_bounds__(256) void combine_out(
    const unsigned short* __restrict__ planes, float* __restrict__ out)
{
  int i = blockIdx.x * blockDim.x + threadIdx.x;   // i < T*DM/8
  float s[8] = {0.f};
  #pragma unroll
  for (int pl = 0; pl < 8; ++pl) {
    us8 v = *(const us8*)&planes[(size_t)pl * T_TOK * DM + (size_t)i * 8];
    #pragma unroll
    for (int jj = 0; jj < 8; ++jj) s[jj] += bf2f(v[jj]);
  }
  float4* o = (float4*)(out + (size_t)i * 8);
  o[0] = make_float4(s[0], s[1], s[2], s[3]);
  o[1] = make_float4(s[4], s[5], s[6], s[7]);
}

// ---------------------------------------------------------------------------
extern "C" void kernel_launch(void* const* d_in, const int* in_sizes, int n_in,
                              void* d_out, int out_size, void* d_ws, size_t ws_size,
                              hipStream_t stream)
{
  const float* x      = (const float*)d_in[0];
  const float* h_prev = (const float*)d_in[1];
  const float* Wp     = (const float*)d_in[2];
  const float* bp     = (const float*)d_in[3];
  const float* W_ih   = (const float*)d_in[4];
  const float* W_hh   = (const float*)d_in[5];
  const float* b_ih   = (const float*)d_in[6];
  const float* b_hh   = (const float*)d_in[7];
  const float* Wr     = (const float*)d_in[8];
  const float* br     = (const float*)d_in[9];
  const float* W1     = (const float*)d_in[10];
  const float* b1     = (const float*)d_in[11];
  const float* W2     = (const float*)d_in[12];
  const float* b2     = (const float*)d_in[13];
  (void)in_sizes; (void)n_in; (void)out_size; (void)ws_size;

  float* out  = (float*)d_out;                        // [T, DM]
  float* hout = out + (size_t)T_TOK * DM;             // [T, PP]

  char* ws = (char*)d_ws;
  // [0, 32M): W1t bf16 (read by gemm1) -> reused as 8 bf16 planes (gemm2)
  unsigned short* W1t    = (unsigned short*)(ws + 0);
  unsigned short* planes = (unsigned short*)(ws + 0);          // 8 x 4 MB
  // [32M, 64M): W2t bf16
  unsigned short* W2t = (unsigned short*)(ws + 33554432);
  // [64M, ~104M): hidden bf16 [10240][DFF]; routing temporaries overlap (dead first)
  unsigned short* hidden = (unsigned short*)(ws + 67108864);   // 40 MB
  float* xp   = (float*)(ws + 67108864);              // [T,128]  2 MB
  float* gs   = (float*)(ws + 69206016);              // [T,512]  8 MB
  float* Bcat = (float*)(ws + 77594624);              // [512,256] 512 KB
  float* bcat = (float*)(ws + 78118912);              // [512]
  // [104M, ~114M): xg bf16 [10240][DM]
  unsigned short* xg = (unsigned short*)(ws + 109051904);
  // [~114M+): router lists
  float* wgt   = (float*)(ws + 119537664);            // [E,T]
  int* tokslot = (int*)(ws + 119799808);              // [E,T]
  int* cnt     = (int*)(ws + 120061952);              // [E]
  int* offPad  = (int*)(ws + 120062016);              // [E+1]

  zero_cnt<<<1, 64, 0, stream>>>(cnt);

  // routing chain (f32 for exact top-k behavior)
  prep_gates<<<512, 256, 0, stream>>>(W_ih, W_hh, b_ih, b_hh, Bcat, bcat);
  sgemm_nt_bias<<<dim3(T_TOK/64, PP/64), 256, 0, stream>>>(x, Wp, bp, xp, T_TOK, PP, DM);
  sgemm_cat<<<dim3(T_TOK/64, 512/64), 256, 0, stream>>>(xp, h_prev, Bcat, bcat, gs);
  gru_elem2<<<(T_TOK * PP) / 256, 256, 0, stream>>>(gs, h_prev, hout);
  router_topk<<<T_TOK / 4, 256, 0, stream>>>(hout, Wr, br, wgt, tokslot, cnt);
  calc_off<<<1, 64, 0, stream>>>(cnt, offPad);

  // weight transpose+convert
  transpose_cvt<<<dim3(DFF/64, DM/64, NE), 256, 0, stream>>>(W1, W1t, DM, DFF);
  transpose_cvt<<<dim3(DM/64, DFF/64, NE), 256, 0, stream>>>(W2, W2t, DFF, DM);

  // expert path: W-resident-in-LDS blocks, activations straight from L2
  gather_x<<<dim3(32, NE), 256, 0, stream>>>(x, tokslot, cnt, offPad, xg);
  expert_gemm1<<<512, 256, 0, stream>>>(xg, W1t, b1, cnt, offPad, hidden);
  expert_gemm2<<<512, 256, 0, stream>>>(hidden, W2t, b2, cnt, offPad, tokslot, wgt, planes);
  combine_out<<<(T_TOK * DM / 8) / 256, 256, 0, stream>>>(planes, out);
}

// Round 6
// 277.548 us; speedup vs baseline: 3.8507x; 1.3411x over previous
//
#include <hip/hip_runtime.h>
#include <cmath>

#define T_TOK 4096
#define DM    512
#define DFF   2048
#define NE    16
#define PP    128

typedef __attribute__((ext_vector_type(8))) short bfrag;      // 8 bf16 (4 VGPRs)
typedef __attribute__((ext_vector_type(4))) float f32x4;
typedef __attribute__((ext_vector_type(8))) unsigned short us8;

__device__ __forceinline__ unsigned short f2bf(float f) {
  unsigned int u = __float_as_uint(f);
  unsigned int r = (u + 0x7FFFu + ((u >> 16) & 1u)) >> 16;
  return (unsigned short)r;
}
__device__ __forceinline__ float bf2f(unsigned short b) {
  return __uint_as_float(((unsigned int)b) << 16);
}

#define GLOAD_LDS16(g, l) __builtin_amdgcn_global_load_lds( \
    (const __attribute__((address_space(1))) void*)(g), \
    (__attribute__((address_space(3))) void*)(l), 16, 0, 0)

// ---------------------------------------------------------------------------
// f32 tiled SGEMM: C[M,N] = A[M,K] * B[N,K]^T + bias[N]   (routing chain)
// ---------------------------------------------------------------------------
__global__ __launch_bounds__(256) void sgemm_nt_bias(
    const float* __restrict__ A, const float* __restrict__ B,
    const float* __restrict__ bias, float* __restrict__ C,
    int M, int N, int K)
{
  __shared__ __align__(16) float As[16][68];
  __shared__ __align__(16) float Bs[16][68];
  const int bm = blockIdx.x * 64;
  const int bn = blockIdx.y * 64;
  const int tid = threadIdx.x;
  const int tx = tid & 15;
  const int ty = tid >> 4;

  float acc[4][4] = {{0.f}};

  for (int k0 = 0; k0 < K; k0 += 16) {
    {
      int r  = tid >> 2;
      int c4 = (tid & 3) * 4;
      float4 v = *(const float4*)(A + (size_t)(bm + r) * K + k0 + c4);
      As[c4+0][r] = v.x; As[c4+1][r] = v.y; As[c4+2][r] = v.z; As[c4+3][r] = v.w;
    }
    {
      int r  = tid >> 2;
      int c4 = (tid & 3) * 4;
      float4 v = *(const float4*)(B + (size_t)(bn + r) * K + k0 + c4);
      Bs[c4+0][r] = v.x; Bs[c4+1][r] = v.y; Bs[c4+2][r] = v.z; Bs[c4+3][r] = v.w;
    }
    __syncthreads();
    #pragma unroll
    for (int k = 0; k < 16; ++k) {
      float4 a4 = *(const float4*)&As[k][ty*4];
      float4 b4 = *(const float4*)&Bs[k][tx*4];
      float a[4] = {a4.x, a4.y, a4.z, a4.w};
      float b[4] = {b4.x, b4.y, b4.z, b4.w};
      #pragma unroll
      for (int i = 0; i < 4; ++i)
        #pragma unroll
        for (int j = 0; j < 4; ++j)
          acc[i][j] += a[i] * b[j];
    }
    __syncthreads();
  }
  #pragma unroll
  for (int i = 0; i < 4; ++i) {
    int row = bm + ty*4 + i;
    #pragma unroll
    for (int j = 0; j < 4; ++j) {
      int col = bn + tx*4 + j;
      C[(size_t)row * N + col] = acc[i][j] + bias[col];
    }
  }
}

// ---------------------------------------------------------------------------
// Fused gate GEMM: C[T,512] = [xp | h_prev] @ Bcat^T + bcat   (K = 256)
// ---------------------------------------------------------------------------
__global__ __launch_bounds__(256) void sgemm_cat(
    const float* __restrict__ A1, const float* __restrict__ A2,
    const float* __restrict__ B, const float* __restrict__ bias,
    float* __restrict__ C)
{
  __shared__ __align__(16) float As[16][68];
  __shared__ __align__(16) float Bs[16][68];
  const int bm = blockIdx.x * 64;
  const int bn = blockIdx.y * 64;
  const int tid = threadIdx.x;
  const int tx = tid & 15;
  const int ty = tid >> 4;

  float acc[4][4] = {{0.f}};

  for (int k0 = 0; k0 < 256; k0 += 16) {
    {
      int r  = tid >> 2;
      int c4 = (tid & 3) * 4;
      const float* src = (k0 < 128) ? (A1 + (size_t)(bm + r) * 128 + k0 + c4)
                                    : (A2 + (size_t)(bm + r) * 128 + (k0 - 128) + c4);
      float4 v = *(const float4*)src;
      As[c4+0][r] = v.x; As[c4+1][r] = v.y; As[c4+2][r] = v.z; As[c4+3][r] = v.w;
    }
    {
      int r  = tid >> 2;
      int c4 = (tid & 3) * 4;
      float4 v = *(const float4*)(B + (size_t)(bn + r) * 256 + k0 + c4);
      Bs[c4+0][r] = v.x; Bs[c4+1][r] = v.y; Bs[c4+2][r] = v.z; Bs[c4+3][r] = v.w;
    }
    __syncthreads();
    #pragma unroll
    for (int k = 0; k < 16; ++k) {
      float4 a4 = *(const float4*)&As[k][ty*4];
      float4 b4 = *(const float4*)&Bs[k][tx*4];
      float a[4] = {a4.x, a4.y, a4.z, a4.w};
      float b[4] = {b4.x, b4.y, b4.z, b4.w};
      #pragma unroll
      for (int i = 0; i < 4; ++i)
        #pragma unroll
        for (int j = 0; j < 4; ++j)
          acc[i][j] += a[i] * b[j];
    }
    __syncthreads();
  }
  #pragma unroll
  for (int i = 0; i < 4; ++i) {
    int row = bm + ty*4 + i;
    #pragma unroll
    for (int j = 0; j < 4; ++j) {
      int col = bn + tx*4 + j;
      C[(size_t)row * 512 + col] = acc[i][j] + bias[col];
    }
  }
}

// build Bcat [512][256] and bcat [512]; also zero cnt (block 0)
__global__ void prep_gates(const float* __restrict__ W_ih, const float* __restrict__ W_hh,
                           const float* __restrict__ b_ih, const float* __restrict__ b_hh,
                           float* __restrict__ Bcat, float* __restrict__ bcat,
                           int* __restrict__ cnt)
{
  int id = blockIdx.x * 256 + threadIdx.x;   // 131072
  if (blockIdx.x == 0 && threadIdx.x < NE) cnt[threadIdx.x] = 0;
  int n = id >> 8, k = id & 255;
  float v;
  if (n < 256)      v = (k < 128) ? W_ih[n * 128 + k] : W_hh[n * 128 + k - 128];
  else if (n < 384) v = (k < 128) ? W_ih[n * 128 + k] : 0.f;
  else              v = (k < 128) ? 0.f : W_hh[(n - 128) * 128 + k - 128];
  Bcat[n * 256 + k] = v;
  if (id < 512) {
    float b = (id < 256) ? (b_ih[id] + b_hh[id])
            : (id < 384) ? b_ih[id] : b_hh[id - 128];
    bcat[id] = b;
  }
}

// ---------------------------------------------------------------------------
// GRU elementwise from fused gate buffer s[T,512]
// ---------------------------------------------------------------------------
__global__ void gru_elem2(const float* __restrict__ s, const float* __restrict__ hprev,
                          float* __restrict__ hout)
{
  int i = blockIdx.x * blockDim.x + threadIdx.x;
  int t = i >> 7, p = i & 127;
  const float* sr = s + (size_t)t * 512;
  float rz = sr[p], zz = sr[128 + p], xn = sr[256 + p], hn = sr[384 + p];
  float r = 1.f / (1.f + expf(-rz));
  float z = 1.f / (1.f + expf(-zz));
  float n = tanhf(xn + r * hn);
  hout[i] = (1.f - z) * n + z * hprev[i];
}

// ---------------------------------------------------------------------------
// Router v2: one token per thread, Wr in LDS, per-block histogram ranking.
// 64 blocks x 64 threads. Selection semantics identical (strict > scan).
// ---------------------------------------------------------------------------
__global__ __launch_bounds__(64) void router_topk2(
    const float* __restrict__ h, const float* __restrict__ Wr,
    const float* __restrict__ br,
    float* __restrict__ wgt, int* __restrict__ tokslot,
    int* __restrict__ cnt)
{
  __shared__ float4 wr4[NE * 32];     // 8 KB: expert e, chunk i at [e*32+i]
  __shared__ float br_s[NE];
  __shared__ int hist[NE];
  __shared__ int basex[NE];

  int tid = threadIdx.x;
  #pragma unroll
  for (int i = 0; i < 8; ++i)
    wr4[tid + i * 64] = ((const float4*)Wr)[tid + i * 64];
  if (tid < NE) { br_s[tid] = br[tid]; hist[tid] = 0; }
  __syncthreads();

  int t = blockIdx.x * 64 + tid;
  const float4* hr = (const float4*)(h + (size_t)t * PP);

  float logit[NE];
  #pragma unroll
  for (int e = 0; e < NE; ++e) logit[e] = 0.f;
  #pragma unroll 4
  for (int i = 0; i < 32; ++i) {
    float4 v = hr[i];
    #pragma unroll
    for (int e = 0; e < NE; ++e) {
      float4 w = wr4[e * 32 + i];
      logit[e] += v.x * w.x + v.y * w.y + v.z * w.z + v.w * w.w;
    }
  }
  #pragma unroll
  for (int e = 0; e < NE; ++e) logit[e] += br_s[e];

  float mx = logit[0];
  #pragma unroll
  for (int e = 1; e < NE; ++e) mx = fmaxf(mx, logit[e]);
  float p[NE];
  #pragma unroll
  for (int e = 0; e < NE; ++e) p[e] = expf(logit[e] - mx);
  int i0 = 0; float m0 = p[0];
  #pragma unroll
  for (int e = 1; e < NE; ++e) { if (p[e] > m0) { m0 = p[e]; i0 = e; } }
  int i1 = -1; float m1 = -1.f;
  #pragma unroll
  for (int e = 0; e < NE; ++e) { if (e != i0 && p[e] > m1) { m1 = p[e]; i1 = e; } }
  float inv = 1.f / (m0 + m1);
  float w0 = m0 * inv, w1 = m1 * inv;

  int r0 = atomicAdd(&hist[i0], 1);   // LDS atomics — cheap
  int r1 = atomicAdd(&hist[i1], 1);
  __syncthreads();
  if (tid < NE && hist[tid] > 0) basex[tid] = atomicAdd(&cnt[tid], hist[tid]);
  __syncthreads();

  int p0 = basex[i0] + r0;
  tokslot[(size_t)i0 * T_TOK + p0] = (t << 1);
  wgt[(size_t)i0 * T_TOK + p0] = w0;
  int p1 = basex[i1] + r1;
  tokslot[(size_t)i1 * T_TOK + p1] = (t << 1) | 1;
  wgt[(size_t)i1 * T_TOK + p1] = w1;
}

__global__ void calc_off(const int* __restrict__ cnt, int* __restrict__ offPad) {
  if (threadIdx.x == 0) {
    int s = 0;
    for (int e = 0; e < NE; ++e) { offPad[e] = s; s += (cnt[e] + 127) & ~127; }
    offPad[NE] = s;
  }
}

// ---------------------------------------------------------------------------
// Transpose+convert: in [E][K][N] f32 -> out [E][N][K] bf16  (64x64 tiles)
// ---------------------------------------------------------------------------
__global__ __launch_bounds__(256) void transpose_cvt(
    const float* __restrict__ in, unsigned short* __restrict__ out, int K, int N)
{
  __shared__ float tl[64][65];
  int e = blockIdx.z, kt = blockIdx.y, nt = blockIdx.x;
  const float* ib = in + (size_t)e * K * N + (size_t)(kt * 64) * N + nt * 64;
  int t = threadIdx.x;
  int r = t >> 2, c0 = (t & 3) * 16;
  #pragma unroll
  for (int i = 0; i < 4; ++i) {
    float4 v = *(const float4*)(ib + (size_t)r * N + c0 + i * 4);
    tl[r][c0+i*4+0] = v.x; tl[r][c0+i*4+1] = v.y;
    tl[r][c0+i*4+2] = v.z; tl[r][c0+i*4+3] = v.w;
  }
  __syncthreads();
  unsigned short* ob = out + (size_t)e * N * K + (size_t)(nt * 64) * K + kt * 64;
  #pragma unroll
  for (int i = 0; i < 2; ++i) {
    int u = t + i * 256;
    int n = u >> 3, k0 = (u & 7) * 8;
    us8 o;
    #pragma unroll
    for (int j = 0; j < 8; ++j) o[j] = f2bf(tl[k0 + j][n]);
    *(us8*)(ob + (size_t)n * K + k0) = o;
  }
}

// ---------------------------------------------------------------------------
// Gather routed tokens -> compact padded bf16 xg [rows][DM]
// ---------------------------------------------------------------------------
__global__ __launch_bounds__(256) void gather_x(
    const float* __restrict__ x, const int* __restrict__ tokslot,
    const int* __restrict__ cnt, const int* __restrict__ offPad,
    unsigned short* __restrict__ xg)
{
  int e = blockIdx.y;
  int n = cnt[e];
  int npad = (n + 127) & ~127;
  int r0 = blockIdx.x * 128;
  if (r0 >= npad) return;
  int t = threadIdx.x;
  int r = r0 + (t >> 1);
  int half = t & 1;
  unsigned short* orow = xg + (size_t)(offPad[e] + r) * DM + half * 256;
  if (r >= n) {
    us8 z = {0,0,0,0,0,0,0,0};
    #pragma unroll
    for (int i = 0; i < 32; ++i) *(us8*)(orow + i * 8) = z;
    return;
  }
  int tok = tokslot[(size_t)e * T_TOK + r] >> 1;
  const float* irow = x + (size_t)tok * DM + half * 256;
  #pragma unroll
  for (int i = 0; i < 32; ++i) {
    float4 a = *(const float4*)(irow + i * 8);
    float4 b = *(const float4*)(irow + i * 8 + 4);
    us8 o;
    o[0]=f2bf(a.x); o[1]=f2bf(a.y); o[2]=f2bf(a.z); o[3]=f2bf(a.w);
    o[4]=f2bf(b.x); o[5]=f2bf(b.y); o[6]=f2bf(b.z); o[7]=f2bf(b.w);
    *(us8*)(orow + i * 8) = o;
  }
}

// ---------------------------------------------------------------------------
// GEMM1: hidden = relu(xg @ W1t^T + b1)  -- W slice resident in LDS
// ---------------------------------------------------------------------------
__global__ __launch_bounds__(256) void expert_gemm1(
    const unsigned short* __restrict__ xg, const unsigned short* __restrict__ W1t,
    const float* __restrict__ b1,
    const int* __restrict__ cnt, const int* __restrict__ offPad,
    unsigned short* __restrict__ hidden)
{
  __shared__ unsigned short wlds[64 * 512];   // 64 KB, row stride 1024 B
  int bid = blockIdx.x;
  int xcd = bid & 7, j = bid >> 3;
  int e  = xcd * 2 + (j >> 5);
  int nb = (j & 31) * 64;
  int t = threadIdx.x, lane = t & 63, wv = t >> 6;
  int l15 = lane & 15, lg = lane >> 4;

  const unsigned short* w1b = W1t + ((size_t)e * DFF + nb) * DM;
  #pragma unroll
  for (int i = 0; i < 16; ++i) {
    int s = t + i * 256;                 // 0..4095 16B slots
    int r = s >> 6, c = s & 63;
    int cs = (c & 56) | ((c & 7) ^ (r & 7));
    GLOAD_LDS16(w1b + (size_t)r * DM + (cs << 3), &wlds[s * 8]);
  }
  __syncthreads();

  int npad = (cnt[e] + 127) & ~127;
  int ntiles = npad >> 7;
  int wm = wv * 32;
  int ebase = offPad[e];

  for (int tile = 0; tile < ntiles; ++tile) {
    int rbase = ebase + tile * 128 + wm;
    f32x4 acc[2][4];
    #pragma unroll
    for (int i = 0; i < 2; ++i)
      #pragma unroll
      for (int jj = 0; jj < 4; ++jj) acc[i][jj] = (f32x4){0.f, 0.f, 0.f, 0.f};

    #pragma unroll 2
    for (int kt = 0; kt < 8; ++kt) {
      #pragma unroll
      for (int kk = 0; kk < 2; ++kk) {
        int cidx = kt * 8 + kk * 4 + lg;         // 16B chunk index in [0,64)
        bfrag a[2], b[4];
        #pragma unroll
        for (int fi = 0; fi < 2; ++fi)
          a[fi] = *(const bfrag*)(xg + (size_t)(rbase + fi * 16 + l15) * DM + (cidx << 3));
        #pragma unroll
        for (int fj = 0; fj < 4; ++fj) {
          int row = fj * 16 + l15;
          int cs = (cidx & 56) | ((cidx & 7) ^ (row & 7));
          b[fj] = *(const bfrag*)&wlds[row * 512 + (cs << 3)];
        }
        #pragma unroll
        for (int fi = 0; fi < 2; ++fi)
          #pragma unroll
          for (int fj = 0; fj < 4; ++fj)
            acc[fi][fj] = __builtin_amdgcn_mfma_f32_16x16x32_bf16(a[fi], b[fj], acc[fi][fj], 0, 0, 0);
      }
    }

    #pragma unroll
    for (int fj = 0; fj < 4; ++fj) {
      int col = nb + fj * 16 + l15;
      float bias = b1[(size_t)e * DFF + col];
      #pragma unroll
      for (int fi = 0; fi < 2; ++fi) {
        #pragma unroll
        for (int rg = 0; rg < 4; ++rg) {
          int row = ebase + tile * 128 + wm + fi * 16 + lg * 4 + rg;
          float v = acc[fi][fj][rg] + bias;
          hidden[(size_t)row * DFF + col] = f2bf(v > 0.f ? v : 0.f);
        }
      }
    }
  }
}

// ---------------------------------------------------------------------------
// GEMM2: y = hidden @ W2t^T (+ b2 on kq==0), split-K x4, scatter to 8 planes
// ---------------------------------------------------------------------------
__global__ __launch_bounds__(256) void expert_gemm2(
    const unsigned short* __restrict__ hidden, const unsigned short* __restrict__ W2t,
    const float* __restrict__ b2,
    const int* __restrict__ cnt, const int* __restrict__ offPad,
    const int* __restrict__ tokslot, const float* __restrict__ wgt,
    unsigned short* __restrict__ planes)
{
  __shared__ unsigned short wlds[64 * 512];   // 64 KB
  int bid = blockIdx.x;
  int xcd = bid & 7, j = bid >> 3;
  int e   = xcd * 2 + (j >> 5);
  int r5  = j & 31;
  int ncb = (r5 & 7) * 64;                    // dm chunk base
  int kq  = r5 >> 3;                          // K quarter
  int kb  = kq * 512;
  int t = threadIdx.x, lane = t & 63, wv = t >> 6;
  int l15 = lane & 15, lg = lane >> 4;

  const unsigned short* w2b = W2t + ((size_t)e * DM + ncb) * DFF + kb;
  #pragma unroll
  for (int i = 0; i < 16; ++i) {
    int s = t + i * 256;
    int r = s >> 6, c = s & 63;
    int cs = (c & 56) | ((c & 7) ^ (r & 7));
    GLOAD_LDS16(w2b + (size_t)r * DFF + (cs << 3), &wlds[s * 8]);
  }
  __syncthreads();

  int n = cnt[e];
  int npad = (n + 127) & ~127;
  int ntiles = npad >> 7;
  int wm = wv * 32;
  int ebase = offPad[e];

  for (int tile = 0; tile < ntiles; ++tile) {
    int rbase = ebase + tile * 128 + wm;
    f32x4 acc[2][4];
    #pragma unroll
    for (int i = 0; i < 2; ++i)
      #pragma unroll
      for (int jj = 0; jj < 4; ++jj) acc[i][jj] = (f32x4){0.f, 0.f, 0.f, 0.f};

    #pragma unroll 2
    for (int kt = 0; kt < 8; ++kt) {
      #pragma unroll
      for (int kk = 0; kk < 2; ++kk) {
        int cidx = kt * 8 + kk * 4 + lg;
        bfrag a[2], b[4];
        #pragma unroll
        for (int fi = 0; fi < 2; ++fi)
          a[fi] = *(const bfrag*)(hidden + (size_t)(rbase + fi * 16 + l15) * DFF + kb + (cidx << 3));
        #pragma unroll
        for (int fj = 0; fj < 4; ++fj) {
          int row = fj * 16 + l15;
          int cs = (cidx & 56) | ((cidx & 7) ^ (row & 7));
          b[fj] = *(const bfrag*)&wlds[row * 512 + (cs << 3)];
        }
        #pragma unroll
        for (int fi = 0; fi < 2; ++fi)
          #pragma unroll
          for (int fj = 0; fj < 4; ++fj)
            acc[fi][fj] = __builtin_amdgcn_mfma_f32_16x16x32_bf16(a[fi], b[fj], acc[fi][fj], 0, 0, 0);
      }
    }

    #pragma unroll
    for (int fi = 0; fi < 2; ++fi) {
      #pragma unroll
      for (int rg = 0; rg < 4; ++rg) {
        int lrow = wm + fi * 16 + lg * 4 + rg;
        int idx = tile * 128 + lrow;
        if (idx >= n) continue;
        int ts = tokslot[(size_t)e * T_TOK + idx];
        float w = wgt[(size_t)e * T_TOK + idx];
        unsigned short* pl = planes + ((size_t)(kq * 2 + (ts & 1)) * T_TOK + (ts >> 1)) * DM;
        #pragma unroll
        for (int fj = 0; fj < 4; ++fj) {
          int col = ncb + fj * 16 + l15;
          float bv = (kq == 0) ? b2[(size_t)e * DM + col] : 0.f;
          pl[col] = f2bf((acc[fi][fj][rg] + bv) * w);
        }
      }
    }
  }
}

// ---------------------------------------------------------------------------
// Combine: out[t][d] = sum over 8 bf16 planes
// ---------------------------------------------------------------------------
__global__ __launch_bounds__(256) void combine_out(
    const unsigned short* __restrict__ planes, float* __restrict__ out)
{
  int i = blockIdx.x * blockDim.x + threadIdx.x;   // i < T*DM/8
  float s[8] = {0.f};
  #pragma unroll
  for (int pl = 0; pl < 8; ++pl) {
    us8 v = *(const us8*)&planes[(size_t)pl * T_TOK * DM + (size_t)i * 8];
    #pragma unroll
    for (int jj = 0; jj < 8; ++jj) s[jj] += bf2f(v[jj]);
  }
  float4* o = (float4*)(out + (size_t)i * 8);
  o[0] = make_float4(s[0], s[1], s[2], s[3]);
  o[1] = make_float4(s[4], s[5], s[6], s[7]);
}

// ---------------------------------------------------------------------------
extern "C" void kernel_launch(void* const* d_in, const int* in_sizes, int n_in,
                              void* d_out, int out_size, void* d_ws, size_t ws_size,
                              hipStream_t stream)
{
  const float* x      = (const float*)d_in[0];
  const float* h_prev = (const float*)d_in[1];
  const float* Wp     = (const float*)d_in[2];
  const float* bp     = (const float*)d_in[3];
  const float* W_ih   = (const float*)d_in[4];
  const float* W_hh   = (const float*)d_in[5];
  const float* b_ih   = (const float*)d_in[6];
  const float* b_hh   = (const float*)d_in[7];
  const float* Wr     = (const float*)d_in[8];
  const float* br     = (const float*)d_in[9];
  const float* W1     = (const float*)d_in[10];
  const float* b1     = (const float*)d_in[11];
  const float* W2     = (const float*)d_in[12];
  const float* b2     = (const float*)d_in[13];
  (void)in_sizes; (void)n_in; (void)out_size; (void)ws_size;

  float* out  = (float*)d_out;                        // [T, DM]
  float* hout = out + (size_t)T_TOK * DM;             // [T, PP]

  char* ws = (char*)d_ws;
  // [0, 32M): W1t bf16 (read by gemm1) -> reused as 8 bf16 planes (gemm2)
  unsigned short* W1t    = (unsigned short*)(ws + 0);
  unsigned short* planes = (unsigned short*)(ws + 0);          // 8 x 4 MB
  // [32M, 64M): W2t bf16
  unsigned short* W2t = (unsigned short*)(ws + 33554432);
  // [64M, ~104M): hidden bf16 [10240][DFF]; routing temporaries overlap (dead first)
  unsigned short* hidden = (unsigned short*)(ws + 67108864);   // 40 MB
  float* xp   = (float*)(ws + 67108864);              // [T,128]  2 MB
  float* gs   = (float*)(ws + 69206016);              // [T,512]  8 MB
  float* Bcat = (float*)(ws + 77594624);              // [512,256] 512 KB
  float* bcat = (float*)(ws + 78118912);              // [512]
  // [104M, ~114M): xg bf16 [10240][DM]
  unsigned short* xg = (unsigned short*)(ws + 109051904);
  // [~114M+): router lists
  float* wgt   = (float*)(ws + 119537664);            // [E,T]
  int* tokslot = (int*)(ws + 119799808);              // [E,T]
  int* cnt     = (int*)(ws + 120061952);              // [E]
  int* offPad  = (int*)(ws + 120062016);              // [E+1]

  // routing chain (f32 for exact top-k behavior); prep_gates also zeroes cnt
  prep_gates<<<512, 256, 0, stream>>>(W_ih, W_hh, b_ih, b_hh, Bcat, bcat, cnt);
  sgemm_nt_bias<<<dim3(T_TOK/64, PP/64), 256, 0, stream>>>(x, Wp, bp, xp, T_TOK, PP, DM);
  sgemm_cat<<<dim3(T_TOK/64, 512/64), 256, 0, stream>>>(xp, h_prev, Bcat, bcat, gs);
  gru_elem2<<<(T_TOK * PP) / 256, 256, 0, stream>>>(gs, h_prev, hout);
  router_topk2<<<64, 64, 0, stream>>>(hout, Wr, br, wgt, tokslot, cnt);
  calc_off<<<1, 64, 0, stream>>>(cnt, offPad);

  // weight transpose+convert
  transpose_cvt<<<dim3(DFF/64, DM/64, NE), 256, 0, stream>>>(W1, W1t, DM, DFF);
  transpose_cvt<<<dim3(DM/64, DFF/64, NE), 256, 0, stream>>>(W2, W2t, DFF, DM);

  // expert path: W-resident-in-LDS blocks, activations straight from L2
  gather_x<<<dim3(32, NE), 256, 0, stream>>>(x, tokslot, cnt, offPad, xg);
  expert_gemm1<<<512, 256, 0, stream>>>(xg, W1t, b1, cnt, offPad, hidden);
  expert_gemm2<<<512, 256, 0, stream>>>(hidden, W2t, b2, cnt, offPad, tokslot, wgt, planes);
  combine_out<<<(T_TOK * DM / 8) / 256, 256, 0, stream>>>(planes, out);
}

// Round 7
// 272.940 us; speedup vs baseline: 3.9157x; 1.0169x over previous
//
#include <hip/hip_runtime.h>
#include <cmath>

#define T_TOK 4096
#define DM    512
#define DFF   2048
#define NE    16
#define PP    128

typedef __attribute__((ext_vector_type(8))) short bfrag;      // 8 bf16 (4 VGPRs)
typedef __attribute__((ext_vector_type(4))) float f32x4;
typedef __attribute__((ext_vector_type(8))) unsigned short us8;

__device__ __forceinline__ unsigned short f2bf(float f) {
  unsigned int u = __float_as_uint(f);
  unsigned int r = (u + 0x7FFFu + ((u >> 16) & 1u)) >> 16;
  return (unsigned short)r;
}
__device__ __forceinline__ float bf2f(unsigned short b) {
  return __uint_as_float(((unsigned int)b) << 16);
}

#define GLOAD_LDS16(g, l) __builtin_amdgcn_global_load_lds( \
    (const __attribute__((address_space(1))) void*)(g), \
    (__attribute__((address_space(3))) void*)(l), 16, 0, 0)

// ---------------------------------------------------------------------------
// f32 tiled SGEMM: C[M,N] = A[M,K] * B[N,K]^T + bias[N]   (routing chain)
// ---------------------------------------------------------------------------
__global__ __launch_bounds__(256) void sgemm_nt_bias(
    const float* __restrict__ A, const float* __restrict__ B,
    const float* __restrict__ bias, float* __restrict__ C,
    int M, int N, int K)
{
  __shared__ __align__(16) float As[16][68];
  __shared__ __align__(16) float Bs[16][68];
  const int bm = blockIdx.x * 64;
  const int bn = blockIdx.y * 64;
  const int tid = threadIdx.x;
  const int tx = tid & 15;
  const int ty = tid >> 4;

  float acc[4][4] = {{0.f}};

  for (int k0 = 0; k0 < K; k0 += 16) {
    {
      int r  = tid >> 2;
      int c4 = (tid & 3) * 4;
      float4 v = *(const float4*)(A + (size_t)(bm + r) * K + k0 + c4);
      As[c4+0][r] = v.x; As[c4+1][r] = v.y; As[c4+2][r] = v.z; As[c4+3][r] = v.w;
    }
    {
      int r  = tid >> 2;
      int c4 = (tid & 3) * 4;
      float4 v = *(const float4*)(B + (size_t)(bn + r) * K + k0 + c4);
      Bs[c4+0][r] = v.x; Bs[c4+1][r] = v.y; Bs[c4+2][r] = v.z; Bs[c4+3][r] = v.w;
    }
    __syncthreads();
    #pragma unroll
    for (int k = 0; k < 16; ++k) {
      float4 a4 = *(const float4*)&As[k][ty*4];
      float4 b4 = *(const float4*)&Bs[k][tx*4];
      float a[4] = {a4.x, a4.y, a4.z, a4.w};
      float b[4] = {b4.x, b4.y, b4.z, b4.w};
      #pragma unroll
      for (int i = 0; i < 4; ++i)
        #pragma unroll
        for (int j = 0; j < 4; ++j)
          acc[i][j] += a[i] * b[j];
    }
    __syncthreads();
  }
  #pragma unroll
  for (int i = 0; i < 4; ++i) {
    int row = bm + ty*4 + i;
    #pragma unroll
    for (int j = 0; j < 4; ++j) {
      int col = bn + tx*4 + j;
      C[(size_t)row * N + col] = acc[i][j] + bias[col];
    }
  }
}

// ---------------------------------------------------------------------------
// Fused gate GEMM: C[T,512] = [xp | h_prev] @ Bcat^T + bcat   (K = 256)
// ---------------------------------------------------------------------------
__global__ __launch_bounds__(256) void sgemm_cat(
    const float* __restrict__ A1, const float* __restrict__ A2,
    const float* __restrict__ B, const float* __restrict__ bias,
    float* __restrict__ C)
{
  __shared__ __align__(16) float As[16][68];
  __shared__ __align__(16) float Bs[16][68];
  const int bm = blockIdx.x * 64;
  const int bn = blockIdx.y * 64;
  const int tid = threadIdx.x;
  const int tx = tid & 15;
  const int ty = tid >> 4;

  float acc[4][4] = {{0.f}};

  for (int k0 = 0; k0 < 256; k0 += 16) {
    {
      int r  = tid >> 2;
      int c4 = (tid & 3) * 4;
      const float* src = (k0 < 128) ? (A1 + (size_t)(bm + r) * 128 + k0 + c4)
                                    : (A2 + (size_t)(bm + r) * 128 + (k0 - 128) + c4);
      float4 v = *(const float4*)src;
      As[c4+0][r] = v.x; As[c4+1][r] = v.y; As[c4+2][r] = v.z; As[c4+3][r] = v.w;
    }
    {
      int r  = tid >> 2;
      int c4 = (tid & 3) * 4;
      float4 v = *(const float4*)(B + (size_t)(bn + r) * 256 + k0 + c4);
      Bs[c4+0][r] = v.x; Bs[c4+1][r] = v.y; Bs[c4+2][r] = v.z; Bs[c4+3][r] = v.w;
    }
    __syncthreads();
    #pragma unroll
    for (int k = 0; k < 16; ++k) {
      float4 a4 = *(const float4*)&As[k][ty*4];
      float4 b4 = *(const float4*)&Bs[k][tx*4];
      float a[4] = {a4.x, a4.y, a4.z, a4.w};
      float b[4] = {b4.x, b4.y, b4.z, b4.w};
      #pragma unroll
      for (int i = 0; i < 4; ++i)
        #pragma unroll
        for (int j = 0; j < 4; ++j)
          acc[i][j] += a[i] * b[j];
    }
    __syncthreads();
  }
  #pragma unroll
  for (int i = 0; i < 4; ++i) {
    int row = bm + ty*4 + i;
    #pragma unroll
    for (int j = 0; j < 4; ++j) {
      int col = bn + tx*4 + j;
      C[(size_t)row * 512 + col] = acc[i][j] + bias[col];
    }
  }
}

// build Bcat [512][256] and bcat [512]; also zero cnt (block 0)
__global__ void prep_gates(const float* __restrict__ W_ih, const float* __restrict__ W_hh,
                           const float* __restrict__ b_ih, const float* __restrict__ b_hh,
                           float* __restrict__ Bcat, float* __restrict__ bcat,
                           int* __restrict__ cnt)
{
  int id = blockIdx.x * 256 + threadIdx.x;   // 131072
  if (blockIdx.x == 0 && threadIdx.x < NE) cnt[threadIdx.x] = 0;
  int n = id >> 8, k = id & 255;
  float v;
  if (n < 256)      v = (k < 128) ? W_ih[n * 128 + k] : W_hh[n * 128 + k - 128];
  else if (n < 384) v = (k < 128) ? W_ih[n * 128 + k] : 0.f;
  else              v = (k < 128) ? 0.f : W_hh[(n - 128) * 128 + k - 128];
  Bcat[n * 256 + k] = v;
  if (id < 512) {
    float b = (id < 256) ? (b_ih[id] + b_hh[id])
            : (id < 384) ? b_ih[id] : b_hh[id - 128];
    bcat[id] = b;
  }
}

// ---------------------------------------------------------------------------
// GRU elementwise from fused gate buffer s[T,512]
// ---------------------------------------------------------------------------
__global__ void gru_elem2(const float* __restrict__ s, const float* __restrict__ hprev,
                          float* __restrict__ hout)
{
  int i = blockIdx.x * blockDim.x + threadIdx.x;
  int t = i >> 7, p = i & 127;
  const float* sr = s + (size_t)t * 512;
  float rz = sr[p], zz = sr[128 + p], xn = sr[256 + p], hn = sr[384 + p];
  float r = 1.f / (1.f + expf(-rz));
  float z = 1.f / (1.f + expf(-zz));
  float n = tanhf(xn + r * hn);
  hout[i] = (1.f - z) * n + z * hprev[i];
}

// ---------------------------------------------------------------------------
// Router v2: one token per thread, Wr in LDS, per-block histogram ranking.
// ---------------------------------------------------------------------------
__global__ __launch_bounds__(64) void router_topk2(
    const float* __restrict__ h, const float* __restrict__ Wr,
    const float* __restrict__ br,
    float* __restrict__ wgt, int* __restrict__ tokslot,
    int* __restrict__ cnt)
{
  __shared__ float4 wr4[NE * 32];     // 8 KB: expert e, chunk i at [e*32+i]
  __shared__ float br_s[NE];
  __shared__ int hist[NE];
  __shared__ int basex[NE];

  int tid = threadIdx.x;
  #pragma unroll
  for (int i = 0; i < 8; ++i)
    wr4[tid + i * 64] = ((const float4*)Wr)[tid + i * 64];
  if (tid < NE) { br_s[tid] = br[tid]; hist[tid] = 0; }
  __syncthreads();

  int t = blockIdx.x * 64 + tid;
  const float4* hr = (const float4*)(h + (size_t)t * PP);

  float logit[NE];
  #pragma unroll
  for (int e = 0; e < NE; ++e) logit[e] = 0.f;
  #pragma unroll 4
  for (int i = 0; i < 32; ++i) {
    float4 v = hr[i];
    #pragma unroll
    for (int e = 0; e < NE; ++e) {
      float4 w = wr4[e * 32 + i];
      logit[e] += v.x * w.x + v.y * w.y + v.z * w.z + v.w * w.w;
    }
  }
  #pragma unroll
  for (int e = 0; e < NE; ++e) logit[e] += br_s[e];

  float mx = logit[0];
  #pragma unroll
  for (int e = 1; e < NE; ++e) mx = fmaxf(mx, logit[e]);
  float p[NE];
  #pragma unroll
  for (int e = 0; e < NE; ++e) p[e] = expf(logit[e] - mx);
  int i0 = 0; float m0 = p[0];
  #pragma unroll
  for (int e = 1; e < NE; ++e) { if (p[e] > m0) { m0 = p[e]; i0 = e; } }
  int i1 = -1; float m1 = -1.f;
  #pragma unroll
  for (int e = 0; e < NE; ++e) { if (e != i0 && p[e] > m1) { m1 = p[e]; i1 = e; } }
  float inv = 1.f / (m0 + m1);
  float w0 = m0 * inv, w1 = m1 * inv;

  int r0 = atomicAdd(&hist[i0], 1);   // LDS atomics — cheap
  int r1 = atomicAdd(&hist[i1], 1);
  __syncthreads();
  if (tid < NE && hist[tid] > 0) basex[tid] = atomicAdd(&cnt[tid], hist[tid]);
  __syncthreads();

  int p0 = basex[i0] + r0;
  tokslot[(size_t)i0 * T_TOK + p0] = (t << 1);
  wgt[(size_t)i0 * T_TOK + p0] = w0;
  int p1 = basex[i1] + r1;
  tokslot[(size_t)i1 * T_TOK + p1] = (t << 1) | 1;
  wgt[(size_t)i1 * T_TOK + p1] = w1;
}

__global__ void calc_off(const int* __restrict__ cnt, int* __restrict__ offPad) {
  if (threadIdx.x == 0) {
    int s = 0;
    for (int e = 0; e < NE; ++e) { offPad[e] = s; s += (cnt[e] + 127) & ~127; }
    offPad[NE] = s;
  }
}

// ---------------------------------------------------------------------------
// Transpose+convert: in [E][K][N] f32 -> out [E][N][K] bf16  (64x64 tiles)
// ---------------------------------------------------------------------------
__global__ __launch_bounds__(256) void transpose_cvt(
    const float* __restrict__ in, unsigned short* __restrict__ out, int K, int N)
{
  __shared__ float tl[64][65];
  int e = blockIdx.z, kt = blockIdx.y, nt = blockIdx.x;
  const float* ib = in + (size_t)e * K * N + (size_t)(kt * 64) * N + nt * 64;
  int t = threadIdx.x;
  int r = t >> 2, c0 = (t & 3) * 16;
  #pragma unroll
  for (int i = 0; i < 4; ++i) {
    float4 v = *(const float4*)(ib + (size_t)r * N + c0 + i * 4);
    tl[r][c0+i*4+0] = v.x; tl[r][c0+i*4+1] = v.y;
    tl[r][c0+i*4+2] = v.z; tl[r][c0+i*4+3] = v.w;
  }
  __syncthreads();
  unsigned short* ob = out + (size_t)e * N * K + (size_t)(nt * 64) * K + kt * 64;
  #pragma unroll
  for (int i = 0; i < 2; ++i) {
    int u = t + i * 256;
    int n = u >> 3, k0 = (u & 7) * 8;
    us8 o;
    #pragma unroll
    for (int j = 0; j < 8; ++j) o[j] = f2bf(tl[k0 + j][n]);
    *(us8*)(ob + (size_t)n * K + k0) = o;
  }
}

// ---------------------------------------------------------------------------
// Gather routed tokens -> compact padded bf16 xg [rows][DM]
// ---------------------------------------------------------------------------
__global__ __launch_bounds__(256) void gather_x(
    const float* __restrict__ x, const int* __restrict__ tokslot,
    const int* __restrict__ cnt, const int* __restrict__ offPad,
    unsigned short* __restrict__ xg)
{
  int e = blockIdx.y;
  int n = cnt[e];
  int npad = (n + 127) & ~127;
  int r0 = blockIdx.x * 128;
  if (r0 >= npad) return;
  int t = threadIdx.x;
  int r = r0 + (t >> 1);
  int half = t & 1;
  unsigned short* orow = xg + (size_t)(offPad[e] + r) * DM + half * 256;
  if (r >= n) {
    us8 z = {0,0,0,0,0,0,0,0};
    #pragma unroll
    for (int i = 0; i < 32; ++i) *(us8*)(orow + i * 8) = z;
    return;
  }
  int tok = tokslot[(size_t)e * T_TOK + r] >> 1;
  const float* irow = x + (size_t)tok * DM + half * 256;
  #pragma unroll
  for (int i = 0; i < 32; ++i) {
    float4 a = *(const float4*)(irow + i * 8);
    float4 b = *(const float4*)(irow + i * 8 + 4);
    us8 o;
    o[0]=f2bf(a.x); o[1]=f2bf(a.y); o[2]=f2bf(a.z); o[3]=f2bf(a.w);
    o[4]=f2bf(b.x); o[5]=f2bf(b.y); o[6]=f2bf(b.z); o[7]=f2bf(b.w);
    *(us8*)(orow + i * 8) = o;
  }
}

// ---------------------------------------------------------------------------
// GEMM1: hidden = relu(xg @ W1t^T + b1)  -- W slice resident in LDS.
// 512 thr / 8 waves (4 waves/SIMD), wave = 32 rows x 64 cols, row-tile 256.
// Odd 128-row tails clamp back 128 (duplicate identical work, deterministic).
// ---------------------------------------------------------------------------
__global__ __launch_bounds__(512, 4) void expert_gemm1(
    const unsigned short* __restrict__ xg, const unsigned short* __restrict__ W1t,
    const float* __restrict__ b1,
    const int* __restrict__ cnt, const int* __restrict__ offPad,
    unsigned short* __restrict__ hidden)
{
  __shared__ unsigned short wlds[64 * 512];   // 64 KB, row stride 1024 B
  int bid = blockIdx.x;
  int xcd = bid & 7, j = bid >> 3;
  int e  = xcd * 2 + (j >> 5);
  int nb = (j & 31) * 64;
  int t = threadIdx.x, lane = t & 63, wv = t >> 6;   // wv 0..7
  int l15 = lane & 15, lg = lane >> 4;
  int wm = wv * 32;

  const unsigned short* w1b = W1t + ((size_t)e * DFF + nb) * DM;
  #pragma unroll
  for (int i = 0; i < 8; ++i) {
    int s = t + i * 512;                 // 0..4095 16B slots
    int r = s >> 6, c = s & 63;
    int cs = (c & 56) | ((c & 7) ^ (r & 7));
    GLOAD_LDS16(w1b + (size_t)r * DM + (cs << 3), &wlds[s * 8]);
  }
  __syncthreads();

  int npad = (cnt[e] + 127) & ~127;
  int ebase = offPad[e];

  for (int tb = 0; tb < npad; tb += 256) {
    int roff[2];
    #pragma unroll
    for (int fi = 0; fi < 2; ++fi) {
      int r0 = wm + fi * 16;
      roff[fi] = (tb + r0 >= npad) ? r0 - 128 : r0;
    }
    f32x4 acc[2][4];
    #pragma unroll
    for (int i = 0; i < 2; ++i)
      #pragma unroll
      for (int jj = 0; jj < 4; ++jj) acc[i][jj] = (f32x4){0.f, 0.f, 0.f, 0.f};

    #pragma unroll 2
    for (int kt = 0; kt < 8; ++kt) {
      #pragma unroll
      for (int kk = 0; kk < 2; ++kk) {
        int cidx = kt * 8 + kk * 4 + lg;         // 16B chunk index in [0,64)
        bfrag a[2], b[4];
        #pragma unroll
        for (int fi = 0; fi < 2; ++fi)
          a[fi] = *(const bfrag*)(xg + (size_t)(ebase + tb + roff[fi] + l15) * DM + (cidx << 3));
        #pragma unroll
        for (int fj = 0; fj < 4; ++fj) {
          int row = fj * 16 + l15;
          int cs = (cidx & 56) | ((cidx & 7) ^ (row & 7));
          b[fj] = *(const bfrag*)&wlds[row * 512 + (cs << 3)];
        }
        #pragma unroll
        for (int fi = 0; fi < 2; ++fi)
          #pragma unroll
          for (int fj = 0; fj < 4; ++fj)
            acc[fi][fj] = __builtin_amdgcn_mfma_f32_16x16x32_bf16(a[fi], b[fj], acc[fi][fj], 0, 0, 0);
      }
    }

    #pragma unroll
    for (int fj = 0; fj < 4; ++fj) {
      int col = nb + fj * 16 + l15;
      float bias = b1[(size_t)e * DFF + col];
      #pragma unroll
      for (int fi = 0; fi < 2; ++fi) {
        #pragma unroll
        for (int rg = 0; rg < 4; ++rg) {
          int row = ebase + tb + roff[fi] + lg * 4 + rg;
          float v = acc[fi][fj][rg] + bias;
          hidden[(size_t)row * DFF + col] = f2bf(v > 0.f ? v : 0.f);
        }
      }
    }
  }
}

// ---------------------------------------------------------------------------
// GEMM2: y = hidden @ W2t^T (+ b2 on kq==0), split-K x4, scatter to 8 planes.
// Same 8-wave W-resident structure as GEMM1.
// ---------------------------------------------------------------------------
__global__ __launch_bounds__(512, 4) void expert_gemm2(
    const unsigned short* __restrict__ hidden, const unsigned short* __restrict__ W2t,
    const float* __restrict__ b2,
    const int* __restrict__ cnt, const int* __restrict__ offPad,
    const int* __restrict__ tokslot, const float* __restrict__ wgt,
    unsigned short* __restrict__ planes)
{
  __shared__ unsigned short wlds[64 * 512];   // 64 KB
  int bid = blockIdx.x;
  int xcd = bid & 7, j = bid >> 3;
  int e   = xcd * 2 + (j >> 5);
  int r5  = j & 31;
  int ncb = (r5 & 7) * 64;                    // dm chunk base
  int kq  = r5 >> 3;                          // K quarter
  int kb  = kq * 512;
  int t = threadIdx.x, lane = t & 63, wv = t >> 6;
  int l15 = lane & 15, lg = lane >> 4;
  int wm = wv * 32;

  const unsigned short* w2b = W2t + ((size_t)e * DM + ncb) * DFF + kb;
  #pragma unroll
  for (int i = 0; i < 8; ++i) {
    int s = t + i * 512;
    int r = s >> 6, c = s & 63;
    int cs = (c & 56) | ((c & 7) ^ (r & 7));
    GLOAD_LDS16(w2b + (size_t)r * DFF + (cs << 3), &wlds[s * 8]);
  }
  __syncthreads();

  int n = cnt[e];
  int npad = (n + 127) & ~127;
  int ebase = offPad[e];

  for (int tb = 0; tb < npad; tb += 256) {
    int roff[2];
    #pragma unroll
    for (int fi = 0; fi < 2; ++fi) {
      int r0 = wm + fi * 16;
      roff[fi] = (tb + r0 >= npad) ? r0 - 128 : r0;
    }
    f32x4 acc[2][4];
    #pragma unroll
    for (int i = 0; i < 2; ++i)
      #pragma unroll
      for (int jj = 0; jj < 4; ++jj) acc[i][jj] = (f32x4){0.f, 0.f, 0.f, 0.f};

    #pragma unroll 2
    for (int kt = 0; kt < 8; ++kt) {
      #pragma unroll
      for (int kk = 0; kk < 2; ++kk) {
        int cidx = kt * 8 + kk * 4 + lg;
        bfrag a[2], b[4];
        #pragma unroll
        for (int fi = 0; fi < 2; ++fi)
          a[fi] = *(const bfrag*)(hidden + (size_t)(ebase + tb + roff[fi] + l15) * DFF + kb + (cidx << 3));
        #pragma unroll
        for (int fj = 0; fj < 4; ++fj) {
          int row = fj * 16 + l15;
          int cs = (cidx & 56) | ((cidx & 7) ^ (row & 7));
          b[fj] = *(const bfrag*)&wlds[row * 512 + (cs << 3)];
        }
        #pragma unroll
        for (int fi = 0; fi < 2; ++fi)
          #pragma unroll
          for (int fj = 0; fj < 4; ++fj)
            acc[fi][fj] = __builtin_amdgcn_mfma_f32_16x16x32_bf16(a[fi], b[fj], acc[fi][fj], 0, 0, 0);
      }
    }

    #pragma unroll
    for (int fi = 0; fi < 2; ++fi) {
      #pragma unroll
      for (int rg = 0; rg < 4; ++rg) {
        int idx = tb + roff[fi] + lg * 4 + rg;
        if (idx >= n) continue;
        int ts = tokslot[(size_t)e * T_TOK + idx];
        float w = wgt[(size_t)e * T_TOK + idx];
        unsigned short* pl = planes + ((size_t)(kq * 2 + (ts & 1)) * T_TOK + (ts >> 1)) * DM;
        #pragma unroll
        for (int fj = 0; fj < 4; ++fj) {
          int col = ncb + fj * 16 + l15;
          float bv = (kq == 0) ? b2[(size_t)e * DM + col] : 0.f;
          pl[col] = f2bf((acc[fi][fj][rg] + bv) * w);
        }
      }
    }
  }
}

// ---------------------------------------------------------------------------
// Combine: out[t][d] = sum over 8 bf16 planes
// ---------------------------------------------------------------------------
__global__ __launch_bounds__(256) void combine_out(
    const unsigned short* __restrict__ planes, float* __restrict__ out)
{
  int i = blockIdx.x * blockDim.x + threadIdx.x;   // i < T*DM/8
  float s[8] = {0.f};
  #pragma unroll
  for (int pl = 0; pl < 8; ++pl) {
    us8 v = *(const us8*)&planes[(size_t)pl * T_TOK * DM + (size_t)i * 8];
    #pragma unroll
    for (int jj = 0; jj < 8; ++jj) s[jj] += bf2f(v[jj]);
  }
  float4* o = (float4*)(out + (size_t)i * 8);
  o[0] = make_float4(s[0], s[1], s[2], s[3]);
  o[1] = make_float4(s[4], s[5], s[6], s[7]);
}

// ---------------------------------------------------------------------------
extern "C" void kernel_launch(void* const* d_in, const int* in_sizes, int n_in,
                              void* d_out, int out_size, void* d_ws, size_t ws_size,
                              hipStream_t stream)
{
  const float* x      = (const float*)d_in[0];
  const float* h_prev = (const float*)d_in[1];
  const float* Wp     = (const float*)d_in[2];
  const float* bp     = (const float*)d_in[3];
  const float* W_ih   = (const float*)d_in[4];
  const float* W_hh   = (const float*)d_in[5];
  const float* b_ih   = (const float*)d_in[6];
  const float* b_hh   = (const float*)d_in[7];
  const float* Wr     = (const float*)d_in[8];
  const float* br     = (const float*)d_in[9];
  const float* W1     = (const float*)d_in[10];
  const float* b1     = (const float*)d_in[11];
  const float* W2     = (const float*)d_in[12];
  const float* b2     = (const float*)d_in[13];
  (void)in_sizes; (void)n_in; (void)out_size; (void)ws_size;

  float* out  = (float*)d_out;                        // [T, DM]
  float* hout = out + (size_t)T_TOK * DM;             // [T, PP]

  char* ws = (char*)d_ws;
  // [0, 32M): W1t bf16 (read by gemm1) -> reused as 8 bf16 planes (gemm2)
  unsigned short* W1t    = (unsigned short*)(ws + 0);
  unsigned short* planes = (unsigned short*)(ws + 0);          // 8 x 4 MB
  // [32M, 64M): W2t bf16
  unsigned short* W2t = (unsigned short*)(ws + 33554432);
  // [64M, ~104M): hidden bf16 [10240][DFF]; routing temporaries overlap (dead first)
  unsigned short* hidden = (unsigned short*)(ws + 67108864);   // 40 MB
  float* xp   = (float*)(ws + 67108864);              // [T,128]  2 MB
  float* gs   = (float*)(ws + 69206016);              // [T,512]  8 MB
  float* Bcat = (float*)(ws + 77594624);              // [512,256] 512 KB
  float* bcat = (float*)(ws + 78118912);              // [512]
  // [104M, ~114M): xg bf16 [10240][DM]
  unsigned short* xg = (unsigned short*)(ws + 109051904);
  // [~114M+): router lists
  float* wgt   = (float*)(ws + 119537664);            // [E,T]
  int* tokslot = (int*)(ws + 119799808);              // [E,T]
  int* cnt     = (int*)(ws + 120061952);              // [E]
  int* offPad  = (int*)(ws + 120062016);              // [E+1]

  // routing chain (f32 for exact top-k behavior); prep_gates also zeroes cnt
  prep_gates<<<512, 256, 0, stream>>>(W_ih, W_hh, b_ih, b_hh, Bcat, bcat, cnt);
  sgemm_nt_bias<<<dim3(T_TOK/64, PP/64), 256, 0, stream>>>(x, Wp, bp, xp, T_TOK, PP, DM);
  sgemm_cat<<<dim3(T_TOK/64, 512/64), 256, 0, stream>>>(xp, h_prev, Bcat, bcat, gs);
  gru_elem2<<<(T_TOK * PP) / 256, 256, 0, stream>>>(gs, h_prev, hout);
  router_topk2<<<64, 64, 0, stream>>>(hout, Wr, br, wgt, tokslot, cnt);
  calc_off<<<1, 64, 0, stream>>>(cnt, offPad);

  // weight transpose+convert
  transpose_cvt<<<dim3(DFF/64, DM/64, NE), 256, 0, stream>>>(W1, W1t, DM, DFF);
  transpose_cvt<<<dim3(DM/64, DFF/64, NE), 256, 0, stream>>>(W2, W2t, DFF, DM);

  // expert path: W-resident-in-LDS blocks, activations straight from L2
  gather_x<<<dim3(32, NE), 256, 0, stream>>>(x, tokslot, cnt, offPad, xg);
  expert_gemm1<<<512, 512, 0, stream>>>(xg, W1t, b1, cnt, offPad, hidden);
  expert_gemm2<<<512, 512, 0, stream>>>(hidden, W2t, b2, cnt, offPad, tokslot, wgt, planes);
  combine_out<<<(T_TOK * DM / 8) / 256, 256, 0, stream>>>(planes, out);
}